// Round 5
// baseline (358.660 us; speedup 1.0000x reference)
//
#include <hip/hip_runtime.h>
#include <math.h>

typedef __attribute__((ext_vector_type(8))) short short8;   // 8 bf16 = 4 VGPRs (MFMA A/B frag)
typedef __attribute__((ext_vector_type(4))) float f32x4;    // MFMA C/D frag

#define MFMA16(a,b,c) __builtin_amdgcn_mfma_f32_16x16x32_bf16((a),(b),(c),0,0,0)

// ---- ws layout: 164 frag-blocks of 1024 B (64 lanes x 16 B) ----
#define WS_B1W1   0
#define WS_B1W2   12
#define WS_LPW1   20
#define WS_LPW2   24
#define WS_A1WIN  28
#define WS_A1WOUT 52
#define WS_F1GW   60
#define WS_F1BW   68
#define WS_B2W1   76
#define WS_B2W2   84
#define WS_A2WIN  92
#define WS_A2WOUT 116
#define WS_F2GW   124
#define WS_F2BW   132
#define WS_B3W1   140
#define WS_B3W2   148
#define WS_OUTW   156
#define WS_FRAGS  164

// RNE f32 -> bf16, round-2-proven bit-twiddle (no inline asm anywhere in this build)
__device__ __forceinline__ unsigned short f2bf(float f) {
  unsigned int u = __float_as_uint(f);
  u = (u + 0x7fffu + ((u >> 16) & 1u)) >> 16;
  return (unsigned short)u;
}

__device__ __forceinline__ short8 pack8(float4 a, float4 b) {
  short8 r;
  r[0]=(short)f2bf(a.x); r[1]=(short)f2bf(a.y); r[2]=(short)f2bf(a.z); r[3]=(short)f2bf(a.w);
  r[4]=(short)f2bf(b.x); r[5]=(short)f2bf(b.y); r[6]=(short)f2bf(b.z); r[7]=(short)f2bf(b.w);
  return r;
}

__device__ __forceinline__ short8 zero8() {
  short8 r;
  #pragma unroll
  for (int j = 0; j < 8; ++j) r[j] = 0;
  return r;
}

// exact bf16 sign flip (for k0-k1 via single MFMA accumulation chain)
__device__ __forceinline__ short8 neg8(short8 a) {
  union { short8 s; unsigned int u[4]; } r;
  r.s = a;
  #pragma unroll
  for (int i = 0; i < 4; ++i) r.u[i] ^= 0x80008000u;
  return r.s;
}

__device__ __forceinline__ f32x4 relu4(f32x4 v) {
  f32x4 r;
  #pragma unroll
  for (int j = 0; j < 4; ++j) r[j] = fmaxf(v[j], 0.0f);
  return r;
}

// ============ prep: weights f32 -> bf16 B-fragments in d_ws ============
// B-frag layout (16x16x32): lane l holds B[k = (l>>4)*8 + j][col = l&15], j=0..7.
__global__ __launch_bounds__(64) void prep_kernel(
    const float* b1w1, const float* b1w2, const float* lpw1, const float* lpw2,
    const float* a1win, const float* a1wout, const float* f1gw, const float* f1bw,
    const float* b2w1, const float* b2w2, const float* a2win, const float* a2wout,
    const float* f2gw, const float* f2bw, const float* b3w1, const float* b3w2,
    const float* outw, unsigned short* ws)
{
  const float* WS_[17] = {b1w1,b1w2,lpw1,lpw2,a1win,a1wout,f1gw,f1bw,b2w1,b2w2,
                          a2win,a2wout,f2gw,f2bw,b3w1,b3w2,outw};
  const int KA[17] = {80,64,40,32,64,64,64,64,64,64,64,64,64,64,64,64,64};
  const int NA[17] = {64,64,32,64,192,64,64,64,64,64,192,64,64,64,64,64,64};
  const int FO[17] = {0,12,20,24,28,52,60,68,76,84,92,116,124,132,140,148,156};

  const int b = blockIdx.x;
  int m = 0;
  #pragma unroll
  for (int i = 1; i < 17; ++i) if (b >= FO[i]) m = i;
  const int f  = b - FO[m];
  const int K  = KA[m], N = NA[m];
  const int kc = (K + 31) >> 5;
  const int n  = f / kc, c = f % kc;

  const int lane = threadIdx.x;
  const int col  = n * 16 + (lane & 15);
  const int kb   = c * 32 + ((lane >> 4) * 8);
  const float* W = WS_[m];

  short8 r;
  #pragma unroll
  for (int j = 0; j < 8; ++j) {
    const int k = kb + j;
    const float v = (k < K) ? W[(size_t)k * N + col] : 0.0f;
    r[j] = (short)f2bf(v);
  }
  *reinterpret_cast<short8*>(ws + (size_t)b * 512 + lane * 8) = r;
}

// ============ main kernel helpers ============
// Per-wave LDS tile: 64 rows x stride 72 bf16 (9216 B).
// A-read: row (s*16+lrow), chunk c -> T + (s*16+lrow)*72 + c*32 + grp*8   (16B aligned)
// C-write: row (s*16+grp*4+j), col n*16+lrow.
__device__ __forceinline__ void stC4(unsigned short* p, f32x4 v) {
  p[0]   = f2bf(v[0]);
  p[72]  = f2bf(v[1]);
  p[144] = f2bf(v[2]);
  p[216] = f2bf(v[3]);
}
__device__ __forceinline__ void ldA4(short8 (&A)[4][2], const unsigned short* Ab) {
  #pragma unroll
  for (int s = 0; s < 4; ++s) {
    A[s][0] = *reinterpret_cast<const short8*>(Ab + s * 1152);
    A[s][1] = *reinterpret_cast<const short8*>(Ab + s * 1152 + 32);
  }
}
// sum over 16-lane groups, broadcast (round-2-proven shuffle form)
__device__ __forceinline__ float rowsum16(float v) {
  v += __shfl_xor(v, 1);
  v += __shfl_xor(v, 2);
  v += __shfl_xor(v, 4);
  v += __shfl_xor(v, 8);
  return v;
}

// ============ main kernel: 4 waves/block, 64 rows/wave ============
__global__ __launch_bounds__(256, 2) void flow_mfma(
    const float* __restrict__ x, const float* __restrict__ t, const float* __restrict__ y,
    const float* __restrict__ b1b1, const float* __restrict__ b1b2,
    const float* __restrict__ lpb1, const float* __restrict__ lpb2,
    const float* __restrict__ a1bin, const float* __restrict__ a1bout,
    const float* __restrict__ f1gb, const float* __restrict__ f1bb,
    const float* __restrict__ b2b1, const float* __restrict__ b2b2,
    const float* __restrict__ a2bin, const float* __restrict__ a2bout,
    const float* __restrict__ f2gb, const float* __restrict__ f2bb,
    const float* __restrict__ b3b1, const float* __restrict__ b3b2,
    const float* __restrict__ outb,
    const unsigned short* __restrict__ ws,
    float* __restrict__ out, int Btotal)
{
  __shared__ __align__(16) unsigned short lds[4][64 * 72];
  const int tid  = threadIdx.x;
  const int lane = tid & 63, wid = tid >> 6;
  const int lrow = lane & 15, grp = lane >> 4;
  const long r0  = ((long)blockIdx.x * 4 + wid) * 64;
  if (r0 >= Btotal) return;
  unsigned short* T  = &lds[wid][0];
  unsigned short* Ab = T + lrow * 72 + grp * 8;
  unsigned short* Cb = T + grp * 4 * 72 + lrow;
  const short8* wsl = reinterpret_cast<const short8*>(ws) + lane;

  // ---- stage x + time features (A-form; chunk2 zero-padded 80..95)
  short8 hA[4][2], tF[4];
  #pragma unroll
  for (int s = 0; s < 4; ++s) {
    const long row = r0 + s * 16 + lrow;
    const float4* xp = reinterpret_cast<const float4*>(x + row * 64) + grp * 2;
    hA[s][0] = pack8(xp[0], xp[1]);
    hA[s][1] = pack8(xp[8], xp[9]);
    const float tv = t[row];
    short8 hp;
    #pragma unroll
    for (int j = 0; j < 8; ++j) {
      const float arg = tv * (3.14159265358979323846f * (float)(1 << j));
      const float sv = sinf(arg), cv = cosf(arg);            // libm (round-1/2-proven)
      const float v = (grp == 0) ? sv : ((grp == 1) ? cv : 0.0f);
      hp[j] = (short)f2bf(v);
    }
    tF[s] = hp;
  }

  // ---- block1 w1: K=80 (3 chunks), ReLU
  #pragma unroll
  for (int n = 0; n < 4; ++n) {
    const short8 B0 = wsl[(WS_B1W1 + n * 3 + 0) * 64];
    const short8 B1 = wsl[(WS_B1W1 + n * 3 + 1) * 64];
    const short8 B2 = wsl[(WS_B1W1 + n * 3 + 2) * 64];
    const float bias = b1b1[n * 16 + lrow];
    #pragma unroll
    for (int s = 0; s < 4; ++s) {
      f32x4 acc = {bias, bias, bias, bias};
      acc = MFMA16(hA[s][0], B0, acc);
      acc = MFMA16(hA[s][1], B1, acc);
      acc = MFMA16(tF[s],    B2, acc);
      stC4(Cb + s * 1152 + n * 16, relu4(acc));
    }
  }
  ldA4(hA, Ab);                       // hA := u (block1 hidden)
  // ---- block1 w2
  #pragma unroll
  for (int n = 0; n < 4; ++n) {
    const short8 B0 = wsl[(WS_B1W2 + n * 2 + 0) * 64];
    const short8 B1 = wsl[(WS_B1W2 + n * 2 + 1) * 64];
    const float bias = b1b2[n * 16 + lrow];
    #pragma unroll
    for (int s = 0; s < 4; ++s) {
      f32x4 acc = {bias, bias, bias, bias};
      acc = MFMA16(hA[s][0], B0, acc);
      acc = MFMA16(hA[s][1], B1, acc);
      stC4(Cb + s * 1152 + n * 16, acc);
    }
  }
  ldA4(hA, Ab);                       // hA := h after block1

  // ---- label projection
  short8 yeA[4][2];
  {
    short8 yA0[4], yA1[4];
    #pragma unroll
    for (int s = 0; s < 4; ++s) {
      const float* yrow = y + (r0 + s * 16 + lrow) * 40;
      yA0[s] = pack8(*reinterpret_cast<const float4*>(yrow + grp * 8),
                     *reinterpret_cast<const float4*>(yrow + grp * 8 + 4));
      yA1[s] = (grp == 0) ? pack8(*reinterpret_cast<const float4*>(yrow + 32),
                                  *reinterpret_cast<const float4*>(yrow + 36))
                          : zero8();
    }
    #pragma unroll
    for (int n = 0; n < 2; ++n) {
      const short8 B0 = wsl[(WS_LPW1 + n * 2 + 0) * 64];
      const short8 B1 = wsl[(WS_LPW1 + n * 2 + 1) * 64];
      const float bias = lpb1[n * 16 + lrow];
      #pragma unroll
      for (int s = 0; s < 4; ++s) {
        f32x4 acc = {bias, bias, bias, bias};
        acc = MFMA16(yA0[s], B0, acc);
        acc = MFMA16(yA1[s], B1, acc);
        stC4(Cb + s * 1152 + n * 16, relu4(acc));
      }
    }
    short8 zA[4];
    #pragma unroll
    for (int s = 0; s < 4; ++s) zA[s] = *reinterpret_cast<const short8*>(Ab + s * 1152);
    #pragma unroll
    for (int n = 0; n < 4; ++n) {
      const short8 B0 = wsl[(WS_LPW2 + n) * 64];
      const float bias = lpb2[n * 16 + lrow];
      #pragma unroll
      for (int s = 0; s < 4; ++s) {
        f32x4 acc = {bias, bias, bias, bias};
        acc = MFMA16(zA[s], B0, acc);
        stC4(Cb + s * 1152 + n * 16, acc);
      }
    }
    ldA4(yeA, Ab);
  }

  // ---- two reps of [attention -> FiLM -> residual block]
  f32x4 hR[4][4];                     // f32 residual carry; ALL indices compile-time (rule #20)
  #pragma unroll 1
  for (int rep = 0; rep < 2; ++rep) {
    const int WIN  = rep ? WS_A2WIN  : WS_A1WIN;
    const int WOUT = rep ? WS_A2WOUT : WS_A1WOUT;
    const int GW   = rep ? WS_F2GW   : WS_F1GW;
    const int BW   = rep ? WS_F2BW   : WS_F1BW;
    const int W1   = rep ? WS_B3W1   : WS_B2W1;
    const int W2   = rep ? WS_B3W2   : WS_B2W2;
    const float* binp  = rep ? a2bin  : a1bin;
    const float* boutp = rep ? a2bout : a1bout;
    const float* gbp   = rep ? f2gb   : f1gb;
    const float* fbp   = rep ? f2bb   : f1bb;
    const float* w1b   = rep ? b3b1   : b2b1;
    const float* w2b   = rep ? b3b2   : b2b2;

    // attention per head n. p0 = sigmoid(0.25*q.(k0-k1)); o = v1 + p0*(v0-v1).
    #pragma unroll 1
    for (int n = 0; n < 4; ++n) {
      const short8 Bq0 = wsl[(WIN + n * 2 + 0) * 64];
      const short8 Bq1 = wsl[(WIN + n * 2 + 1) * 64];
      const short8 Bk0 = wsl[(WIN + (4 + n) * 2 + 0) * 64];
      const short8 Bk1 = wsl[(WIN + (4 + n) * 2 + 1) * 64];
      const float bq = binp[n * 16 + lrow];
      f32x4 pr[4];
      #pragma unroll
      for (int s = 0; s < 4; ++s) {
        f32x4 q = {bq, bq, bq, bq};
        q = MFMA16(hA[s][0], Bq0, q);
        q = MFMA16(hA[s][1], Bq1, q);
        f32x4 kd = {0.0f, 0.0f, 0.0f, 0.0f};
        kd = MFMA16(hA[s][0], Bk0, kd);
        kd = MFMA16(hA[s][1], Bk1, kd);
        kd = MFMA16(neg8(yeA[s][0]), Bk0, kd);   // bias cancels in k0-k1
        kd = MFMA16(neg8(yeA[s][1]), Bk1, kd);
        #pragma unroll
        for (int j = 0; j < 4; ++j) {
          const float d = rowsum16(q[j] * kd[j]);
          pr[s][j] = 1.0f / (1.0f + __expf(-0.25f * d));
        }
      }
      const short8 Bv0 = wsl[(WIN + (8 + n) * 2 + 0) * 64];
      const short8 Bv1 = wsl[(WIN + (8 + n) * 2 + 1) * 64];
      const float bv = binp[128 + n * 16 + lrow];
      #pragma unroll
      for (int s = 0; s < 4; ++s) {
        f32x4 v0 = {bv, bv, bv, bv}, v1 = {bv, bv, bv, bv};
        v0 = MFMA16(hA[s][0],  Bv0, v0);
        v0 = MFMA16(hA[s][1],  Bv1, v0);
        v1 = MFMA16(yeA[s][0], Bv0, v1);
        v1 = MFMA16(yeA[s][1], Bv1, v1);
        f32x4 ov;
        #pragma unroll
        for (int j = 0; j < 4; ++j) ov[j] = fmaf(pr[s][j], v0[j] - v1[j], v1[j]);
        stC4(Cb + s * 1152 + n * 16, ov);
      }
    }
    ldA4(hA, Ab);                     // hA := attn output (A-form)

    // out-proj + FiLM; f32 result kept in hR (fully unrolled -> registers)
    #pragma unroll
    for (int n = 0; n < 4; ++n) {
      const short8 Bo0 = wsl[(WOUT + n * 2 + 0) * 64];
      const short8 Bo1 = wsl[(WOUT + n * 2 + 1) * 64];
      const short8 Bg0 = wsl[(GW + n * 2 + 0) * 64];
      const short8 Bg1 = wsl[(GW + n * 2 + 1) * 64];
      const short8 Bb0 = wsl[(BW + n * 2 + 0) * 64];
      const short8 Bb1 = wsl[(BW + n * 2 + 1) * 64];
      const float bo = boutp[n * 16 + lrow];
      const float bg = gbp[n * 16 + lrow];
      const float bf = fbp[n * 16 + lrow];
      #pragma unroll
      for (int s = 0; s < 4; ++s) {
        f32x4 at = {bo, bo, bo, bo};
        at = MFMA16(hA[s][0], Bo0, at);
        at = MFMA16(hA[s][1], Bo1, at);
        f32x4 g = {bg, bg, bg, bg};
        g = MFMA16(yeA[s][0], Bg0, g);
        g = MFMA16(yeA[s][1], Bg1, g);
        f32x4 fb = {bf, bf, bf, bf};
        fb = MFMA16(yeA[s][0], Bb0, fb);
        fb = MFMA16(yeA[s][1], Bb1, fb);
        f32x4 hv;
        #pragma unroll
        for (int j = 0; j < 4; ++j) hv[j] = fmaf(g[j], at[j], fb[j]);
        hR[s][n] = hv;
        stC4(Cb + s * 1152 + n * 16, hv);
      }
    }
    ldA4(hA, Ab);                     // hA := FiLM output (A-form)

    // residual block w1 (ReLU)
    #pragma unroll 1
    for (int n = 0; n < 4; ++n) {
      const short8 B0 = wsl[(W1 + n * 2 + 0) * 64];
      const short8 B1 = wsl[(W1 + n * 2 + 1) * 64];
      const float bias = w1b[n * 16 + lrow];
      #pragma unroll
      for (int s = 0; s < 4; ++s) {
        f32x4 acc = {bias, bias, bias, bias};
        acc = MFMA16(hA[s][0], B0, acc);
        acc = MFMA16(hA[s][1], B1, acc);
        stC4(Cb + s * 1152 + n * 16, relu4(acc));
      }
    }
    ldA4(hA, Ab);                     // hA := u (MLP hidden)

    // residual block w2 + f32 residual add (fully unrolled -> hR stays in regs)
    #pragma unroll
    for (int n = 0; n < 4; ++n) {
      const short8 B0 = wsl[(W2 + n * 2 + 0) * 64];
      const short8 B1 = wsl[(W2 + n * 2 + 1) * 64];
      const float bias = w2b[n * 16 + lrow];
      #pragma unroll
      for (int s = 0; s < 4; ++s) {
        f32x4 acc = {bias, bias, bias, bias};
        acc = MFMA16(hA[s][0], B0, acc);
        acc = MFMA16(hA[s][1], B1, acc);
        #pragma unroll
        for (int j = 0; j < 4; ++j) acc[j] += hR[s][n][j];
        stC4(Cb + s * 1152 + n * 16, acc);
      }
    }
    ldA4(hA, Ab);                     // hA := h for next rep / final
  }

  // ---- final projection + store (f32, coalesced 64B per 16-lane group)
  #pragma unroll 1
  for (int n = 0; n < 4; ++n) {
    const short8 B0 = wsl[(WS_OUTW + n * 2 + 0) * 64];
    const short8 B1 = wsl[(WS_OUTW + n * 2 + 1) * 64];
    const float bias = outb[n * 16 + lrow];
    #pragma unroll
    for (int s = 0; s < 4; ++s) {
      f32x4 acc = {bias, bias, bias, bias};
      acc = MFMA16(hA[s][0], B0, acc);
      acc = MFMA16(hA[s][1], B1, acc);
      float* ob = out + (r0 + s * 16 + grp * 4) * 64 + n * 16 + lrow;
      #pragma unroll
      for (int j = 0; j < 4; ++j) ob[j * 64] = acc[j];
    }
  }
}

extern "C" void kernel_launch(void* const* d_in, const int* in_sizes, int n_in,
                              void* d_out, int out_size, void* d_ws, size_t ws_size,
                              hipStream_t stream) {
  (void)n_in; (void)out_size; (void)ws_size;
  const float* p[37];
  for (int i = 0; i < 37; ++i) p[i] = (const float*)d_in[i];
  unsigned short* ws = (unsigned short*)d_ws;

  prep_kernel<<<dim3(WS_FRAGS), dim3(64), 0, stream>>>(
      p[23], p[25], p[3], p[5], p[7], p[9], p[15], p[17],
      p[27], p[29], p[11], p[13], p[19], p[21], p[31], p[33], p[35], ws);

  const int B = in_sizes[0] / 64;
  const int grid = (B + 255) / 256;   // 256 rows per block (4 waves x 64)
  flow_mfma<<<dim3(grid), dim3(256), 0, stream>>>(
      p[0], p[1], p[2],
      p[24], p[26],          // b1_b1, b1_b2
      p[4],  p[6],           // lp_b1, lp_b2
      p[8],  p[10],          // a1_bin, a1_bout
      p[16], p[18],          // f1_gb, f1_bb
      p[28], p[30],          // b2_b1, b2_b2
      p[12], p[14],          // a2_bin, a2_bout
      p[20], p[22],          // f2_gb, f2_bb
      p[32], p[34],          // b3_b1, b3_b2
      p[36],                 // out_b
      ws, (float*)d_out, B);
}

// Round 7
// 246.066 us; speedup vs baseline: 1.4576x; 1.4576x over previous
//
#include <hip/hip_runtime.h>
#include <math.h>

typedef __attribute__((ext_vector_type(8))) short   short8;   // 8 fp16 bit-container (4 VGPRs)
typedef __attribute__((ext_vector_type(8))) _Float16 half8;
typedef __attribute__((ext_vector_type(2))) __fp16  fp16x2;   // cvt_pkrtz result type
typedef __attribute__((ext_vector_type(4))) float   f32x4;    // MFMA C/D frag

__device__ __forceinline__ half8 as_h8(short8 s) {
  union { short8 s; half8 h; } u; u.s = s; return u.h;
}
#define MFMA16(a,b,c) __builtin_amdgcn_mfma_f32_16x16x32_f16(as_h8(a), as_h8(b), (c), 0, 0, 0)

// ---- ws layout: 164 frag-blocks of 1024 B (64 lanes x 16 B) ----
#define WS_B1W1   0
#define WS_B1W2   12
#define WS_LPW1   20
#define WS_LPW2   24
#define WS_A1WIN  28
#define WS_A1WOUT 52
#define WS_F1GW   60
#define WS_F1BW   68
#define WS_B2W1   76
#define WS_B2W2   84
#define WS_A2WIN  92
#define WS_A2WOUT 116
#define WS_F2GW   124
#define WS_F2BW   132
#define WS_B3W1   140
#define WS_B3W2   148
#define WS_OUTW   156
#define WS_FRAGS  164

// f32 -> fp16 RNE via HW convert (prep + scalar paths)
__device__ __forceinline__ unsigned short f2h(float f) {
  union { _Float16 h; unsigned short u; } r;
  r.h = (_Float16)f;
  return r.u;
}
// packed f32x2 -> fp16x2 (RTZ), single VALU op, standard clang builtin
__device__ __forceinline__ unsigned int pkrtz(float lo, float hi) {
  union { fp16x2 h; unsigned int u; } r;
  r.h = __builtin_amdgcn_cvt_pkrtz(lo, hi);
  return r.u;
}

__device__ __forceinline__ short8 pack8(float4 a, float4 b) {
  union { unsigned int u[4]; short8 s; } r;
  r.u[0] = pkrtz(a.x, a.y);
  r.u[1] = pkrtz(a.z, a.w);
  r.u[2] = pkrtz(b.x, b.y);
  r.u[3] = pkrtz(b.z, b.w);
  return r.s;
}

__device__ __forceinline__ short8 zero8() {
  short8 r;
  #pragma unroll
  for (int j = 0; j < 8; ++j) r[j] = 0;
  return r;
}

// exact fp16 sign flip (for k0-k1 accumulated in one MFMA chain)
__device__ __forceinline__ short8 neg8(short8 a) {
  union { short8 s; unsigned int u[4]; } r;
  r.s = a;
  #pragma unroll
  for (int i = 0; i < 4; ++i) r.u[i] ^= 0x80008000u;
  return r.s;
}

__device__ __forceinline__ f32x4 relu4(f32x4 v) {
  f32x4 r;
  #pragma unroll
  for (int j = 0; j < 4; ++j) r[j] = fmaxf(v[j], 0.0f);
  return r;
}

// ============ prep: weights f32 -> fp16 B-fragments in d_ws ============
// B-frag layout (16x16x32): lane l holds B[k = (l>>4)*8 + j][col = l&15], j=0..7.
__global__ __launch_bounds__(64) void prep_kernel(
    const float* b1w1, const float* b1w2, const float* lpw1, const float* lpw2,
    const float* a1win, const float* a1wout, const float* f1gw, const float* f1bw,
    const float* b2w1, const float* b2w2, const float* a2win, const float* a2wout,
    const float* f2gw, const float* f2bw, const float* b3w1, const float* b3w2,
    const float* outw, unsigned short* ws)
{
  const float* WS_[17] = {b1w1,b1w2,lpw1,lpw2,a1win,a1wout,f1gw,f1bw,b2w1,b2w2,
                          a2win,a2wout,f2gw,f2bw,b3w1,b3w2,outw};
  const int KA[17] = {80,64,40,32,64,64,64,64,64,64,64,64,64,64,64,64,64};
  const int NA[17] = {64,64,32,64,192,64,64,64,64,64,192,64,64,64,64,64,64};
  const int FO[17] = {0,12,20,24,28,52,60,68,76,84,92,116,124,132,140,148,156};

  const int b = blockIdx.x;
  int m = 0;
  #pragma unroll
  for (int i = 1; i < 17; ++i) if (b >= FO[i]) m = i;
  const int f  = b - FO[m];
  const int K  = KA[m], N = NA[m];
  const int kc = (K + 31) >> 5;
  const int n  = f / kc, c = f % kc;

  const int lane = threadIdx.x;
  const int col  = n * 16 + (lane & 15);
  const int kb   = c * 32 + ((lane >> 4) * 8);
  const float* W = WS_[m];

  short8 r;
  #pragma unroll
  for (int j = 0; j < 8; ++j) {
    const int k = kb + j;
    const float v = (k < K) ? W[(size_t)k * N + col] : 0.0f;
    r[j] = (short)f2h(v);
  }
  *reinterpret_cast<short8*>(ws + (size_t)b * 512 + lane * 8) = r;
}

// ============ main kernel helpers ============
// LDS tile per wave: 16 rows x stride 72 fp16. Abase = L + lrow*72 + grp*8; Cbase = L + grp*288 + lrow.
__device__ __forceinline__ short8 ldA(const unsigned short* Ab, int c) {
  return *reinterpret_cast<const short8*>(Ab + c * 32);
}
__device__ __forceinline__ void stC(unsigned short* Cb, int n, f32x4 v) {
  const unsigned int p01 = pkrtz(v[0], v[1]);
  const unsigned int p23 = pkrtz(v[2], v[3]);
  unsigned short* p = Cb + n * 16;
  p[0]   = (unsigned short)p01;
  p[72]  = (unsigned short)(p01 >> 16);   // ds_write_b16_d16_hi
  p[144] = (unsigned short)p23;
  p[216] = (unsigned short)(p23 >> 16);
}
__device__ __forceinline__ f32x4 gemm1(short8 a0, const short8* wsl, int fb, float bias) {
  f32x4 acc = {bias, bias, bias, bias};
  acc = MFMA16(a0, wsl[fb * 64], acc);
  return acc;
}
__device__ __forceinline__ f32x4 gemm2(short8 a0, short8 a1, const short8* wsl, int fb, float bias) {
  f32x4 acc = {bias, bias, bias, bias};
  acc = MFMA16(a0, wsl[(fb + 0) * 64], acc);
  acc = MFMA16(a1, wsl[(fb + 1) * 64], acc);
  return acc;
}
__device__ __forceinline__ f32x4 gemm3(short8 a0, short8 a1, short8 a2, const short8* wsl, int fb, float bias) {
  f32x4 acc = {bias, bias, bias, bias};
  acc = MFMA16(a0, wsl[(fb + 0) * 64], acc);
  acc = MFMA16(a1, wsl[(fb + 1) * 64], acc);
  acc = MFMA16(a2, wsl[(fb + 2) * 64], acc);
  return acc;
}
// sum over 16-lane groups, broadcast (round-2-proven shuffle form)
__device__ __forceinline__ float rowsum16(float v) {
  v += __shfl_xor(v, 1);
  v += __shfl_xor(v, 2);
  v += __shfl_xor(v, 4);
  v += __shfl_xor(v, 8);
  return v;
}

// ============ main kernel: 4 waves/block, 16 rows/wave (round-2 chassis) ============
__global__ __launch_bounds__(256, 3) void flow_mfma(
    const float* __restrict__ x, const float* __restrict__ t, const float* __restrict__ y,
    const float* __restrict__ b1b1, const float* __restrict__ b1b2,
    const float* __restrict__ lpb1, const float* __restrict__ lpb2,
    const float* __restrict__ a1bin, const float* __restrict__ a1bout,
    const float* __restrict__ f1gb, const float* __restrict__ f1bb,
    const float* __restrict__ b2b1, const float* __restrict__ b2b2,
    const float* __restrict__ a2bin, const float* __restrict__ a2bout,
    const float* __restrict__ f2gb, const float* __restrict__ f2bb,
    const float* __restrict__ b3b1, const float* __restrict__ b3b2,
    const float* __restrict__ outb,
    const unsigned short* __restrict__ ws,
    float* __restrict__ out, int Btotal)
{
  __shared__ __align__(16) unsigned short lds[4][16 * 72];
  const int tid  = threadIdx.x;
  const int lane = tid & 63, wid = tid >> 6;
  const int lrow = lane & 15, grp = lane >> 4;
  const int r0   = (blockIdx.x * 4 + wid) * 16;
  if (r0 >= Btotal) return;
  unsigned short* L  = &lds[wid][0];
  unsigned short* Ab = L + lrow * 72 + grp * 8;   // A-frag read base
  unsigned short* Cb = L + grp * 288 + lrow;      // C-frag write base
  const short8* wsl = reinterpret_cast<const short8*>(ws) + lane;

  // ---- h80 A-frags: x (chunks 0,1) + time features (chunk 2, zero-padded 80..95)
  short8 hA0, hA1, hA2;
  {
    const float4* xp = reinterpret_cast<const float4*>(x + (size_t)(r0 + lrow) * 64) + grp * 2;
    hA0 = pack8(xp[0], xp[1]);
    hA1 = pack8(xp[8], xp[9]);
    const float tv = t[r0 + lrow];
    // sin/cos(pi*t*2^j) by double-angle recursion from one libm pair.
    // fl((pi*2^j)*t) == 2^j * fl(pi*t) bit-exactly, so the argument matches the reference.
    float s = sinf(3.14159265358979323846f * tv);
    float c = cosf(3.14159265358979323846f * tv);
    short8 hp;
    #pragma unroll
    for (int j = 0; j < 8; ++j) {
      const float v = (grp == 0) ? s : ((grp == 1) ? c : 0.0f);
      hp[j] = (short)f2h(v);
      const float s2 = 2.0f * s * c;
      const float c2 = 1.0f - 2.0f * s * s;
      s = s2; c = c2;
    }
    hA2 = hp;
  }

  // ---- block1: h = relu(h80@b1_w1+b1) @ b1_w2 + b2
  #pragma unroll
  for (int n = 0; n < 4; ++n)
    stC(Cb, n, relu4(gemm3(hA0, hA1, hA2, wsl, WS_B1W1 + n * 3, b1b1[n * 16 + lrow])));
  {
    const short8 u0 = ldA(Ab, 0), u1 = ldA(Ab, 1);
    #pragma unroll
    for (int n = 0; n < 4; ++n)
      stC(Cb, n, gemm2(u0, u1, wsl, WS_B1W2 + n * 2, b1b2[n * 16 + lrow]));
  }
  hA0 = ldA(Ab, 0);   // h after block1, A-form
  hA1 = ldA(Ab, 1);

  // ---- label projection: ye = relu(y@lp_w1+b1) @ lp_w2 + b2
  short8 yeA0, yeA1;
  {
    const float* yrow = y + (size_t)(r0 + lrow) * 40;
    const short8 y0 = pack8(*reinterpret_cast<const float4*>(yrow + grp * 8),
                            *reinterpret_cast<const float4*>(yrow + grp * 8 + 4));
    short8 y1 = zero8();
    if (grp == 0)
      y1 = pack8(*reinterpret_cast<const float4*>(yrow + 32),
                 *reinterpret_cast<const float4*>(yrow + 36));
    #pragma unroll
    for (int n = 0; n < 2; ++n)
      stC(Cb, n, relu4(gemm2(y0, y1, wsl, WS_LPW1 + n * 2, lpb1[n * 16 + lrow])));
    const short8 z = ldA(Ab, 0);
    #pragma unroll
    for (int n = 0; n < 4; ++n)
      stC(Cb, n, gemm1(z, wsl, WS_LPW2 + n, lpb2[n * 16 + lrow]));
    yeA0 = ldA(Ab, 0);
    yeA1 = ldA(Ab, 1);
  }

  // ---- two reps of [attention -> FiLM -> residual block]
  f32x4 hC0, hC1, hC2, hC3;    // C-form f32 copy of current h (for residual)
  #pragma unroll 1
  for (int rep = 0; rep < 2; ++rep) {
    const int WIN  = rep ? WS_A2WIN  : WS_A1WIN;
    const int WOUT = rep ? WS_A2WOUT : WS_A1WOUT;
    const int GW   = rep ? WS_F2GW   : WS_F1GW;
    const int BW   = rep ? WS_F2BW   : WS_F1BW;
    const int W1   = rep ? WS_B3W1   : WS_B2W1;
    const int W2   = rep ? WS_B3W2   : WS_B2W2;
    const float* binp  = rep ? a2bin  : a1bin;
    const float* boutp = rep ? a2bout : a1bout;
    const float* gbp   = rep ? f2gb   : f1gb;
    const float* fbp   = rep ? f2bb   : f1bb;
    const float* w1b   = rep ? b3b1   : b2b1;
    const float* w2b   = rep ? b3b2   : b2b2;

    // attention per head n (= 16-col tile). p0 = sigmoid(0.25*q.(k0-k1)); o = v1 + p0*(v0-v1).
    #pragma unroll 1
    for (int n = 0; n < 4; ++n) {
      const f32x4 q = gemm2(hA0, hA1, wsl, WIN + n * 2, binp[n * 16 + lrow]);
      f32x4 kd = {0.0f, 0.0f, 0.0f, 0.0f};
      {
        const short8 Bk0 = wsl[(WIN + (4 + n) * 2 + 0) * 64];
        const short8 Bk1 = wsl[(WIN + (4 + n) * 2 + 1) * 64];
        kd = MFMA16(hA0, Bk0, kd);
        kd = MFMA16(hA1, Bk1, kd);
        kd = MFMA16(neg8(yeA0), Bk0, kd);   // bias cancels in k0-k1
        kd = MFMA16(neg8(yeA1), Bk1, kd);
      }
      const f32x4 v0 = gemm2(hA0,  hA1,  wsl, WIN + (8 + n) * 2, binp[128 + n * 16 + lrow]);
      const f32x4 v1 = gemm2(yeA0, yeA1, wsl, WIN + (8 + n) * 2, binp[128 + n * 16 + lrow]);
      f32x4 ov;
      #pragma unroll
      for (int j = 0; j < 4; ++j) {            // j -> batch row grp*4+j
        const float d = rowsum16(q[j] * kd[j]);
        const float p0 = 1.0f / (1.0f + __expf(-0.25f * d));
        ov[j] = fmaf(p0, v0[j] - v1[j], v1[j]);
      }
      stC(Cb, n, ov);
    }
    const short8 oA0 = ldA(Ab, 0), oA1 = ldA(Ab, 1);

    // out-proj + FiLM fused per tile (manual unroll keeps hC in named regs)
    {
      f32x4 at, g, bb;
      at = gemm2(oA0, oA1, wsl, WOUT + 0, boutp[lrow]);
      g  = gemm2(yeA0, yeA1, wsl, GW + 0, gbp[lrow]);
      bb = gemm2(yeA0, yeA1, wsl, BW + 0, fbp[lrow]);
      #pragma unroll
      for (int j = 0; j < 4; ++j) hC0[j] = fmaf(g[j], at[j], bb[j]);
      stC(Cb, 0, hC0);
      at = gemm2(oA0, oA1, wsl, WOUT + 2, boutp[16 + lrow]);
      g  = gemm2(yeA0, yeA1, wsl, GW + 2, gbp[16 + lrow]);
      bb = gemm2(yeA0, yeA1, wsl, BW + 2, fbp[16 + lrow]);
      #pragma unroll
      for (int j = 0; j < 4; ++j) hC1[j] = fmaf(g[j], at[j], bb[j]);
      stC(Cb, 1, hC1);
      at = gemm2(oA0, oA1, wsl, WOUT + 4, boutp[32 + lrow]);
      g  = gemm2(yeA0, yeA1, wsl, GW + 4, gbp[32 + lrow]);
      bb = gemm2(yeA0, yeA1, wsl, BW + 4, fbp[32 + lrow]);
      #pragma unroll
      for (int j = 0; j < 4; ++j) hC2[j] = fmaf(g[j], at[j], bb[j]);
      stC(Cb, 2, hC2);
      at = gemm2(oA0, oA1, wsl, WOUT + 6, boutp[48 + lrow]);
      g  = gemm2(yeA0, yeA1, wsl, GW + 6, gbp[48 + lrow]);
      bb = gemm2(yeA0, yeA1, wsl, BW + 6, fbp[48 + lrow]);
      #pragma unroll
      for (int j = 0; j < 4; ++j) hC3[j] = fmaf(g[j], at[j], bb[j]);
      stC(Cb, 3, hC3);
    }

    // residual block: h = h + relu(h@w1+b1) @ w2 + b2
    const short8 fA0 = ldA(Ab, 0), fA1 = ldA(Ab, 1);
    #pragma unroll
    for (int n = 0; n < 4; ++n)
      stC(Cb, n, relu4(gemm2(fA0, fA1, wsl, W1 + n * 2, w1b[n * 16 + lrow])));
    const short8 uA0 = ldA(Ab, 0), uA1 = ldA(Ab, 1);
    {
      f32x4 a;
      a = gemm2(uA0, uA1, wsl, W2 + 0, w2b[lrow]);
      #pragma unroll
      for (int j = 0; j < 4; ++j) a[j] += hC0[j];
      stC(Cb, 0, a);
      a = gemm2(uA0, uA1, wsl, W2 + 2, w2b[16 + lrow]);
      #pragma unroll
      for (int j = 0; j < 4; ++j) a[j] += hC1[j];
      stC(Cb, 1, a);
      a = gemm2(uA0, uA1, wsl, W2 + 4, w2b[32 + lrow]);
      #pragma unroll
      for (int j = 0; j < 4; ++j) a[j] += hC2[j];
      stC(Cb, 2, a);
      a = gemm2(uA0, uA1, wsl, W2 + 6, w2b[48 + lrow]);
      #pragma unroll
      for (int j = 0; j < 4; ++j) a[j] += hC3[j];
      stC(Cb, 3, a);
    }
    hA0 = ldA(Ab, 0);
    hA1 = ldA(Ab, 1);
  }

  // ---- final projection + store (f32, coalesced 64B per 16-lane group)
  #pragma unroll 1
  for (int n = 0; n < 4; ++n) {
    const f32x4 a = gemm2(hA0, hA1, wsl, WS_OUTW + n * 2, outb[n * 16 + lrow]);
    float* ob = out + (size_t)(r0 + grp * 4) * 64 + n * 16 + lrow;
    #pragma unroll
    for (int j = 0; j < 4; ++j)
      ob[j * 64] = a[j];
  }
}

extern "C" void kernel_launch(void* const* d_in, const int* in_sizes, int n_in,
                              void* d_out, int out_size, void* d_ws, size_t ws_size,
                              hipStream_t stream) {
  (void)n_in; (void)out_size; (void)ws_size;
  const float* p[37];
  for (int i = 0; i < 37; ++i) p[i] = (const float*)d_in[i];
  unsigned short* ws = (unsigned short*)d_ws;

  prep_kernel<<<dim3(WS_FRAGS), dim3(64), 0, stream>>>(
      p[23], p[25], p[3], p[5], p[7], p[9], p[15], p[17],
      p[27], p[29], p[11], p[13], p[19], p[21], p[31], p[33], p[35], ws);

  const int B = in_sizes[0] / 64;
  const int grid = (B + 63) / 64;
  flow_mfma<<<dim3(grid), dim3(256), 0, stream>>>(
      p[0], p[1], p[2],
      p[24], p[26],          // b1_b1, b1_b2
      p[4],  p[6],           // lp_b1, lp_b2
      p[8],  p[10],          // a1_bin, a1_bout
      p[16], p[18],          // f1_gb, f1_bb
      p[28], p[30],          // b2_b1, b2_b2
      p[12], p[14],          // a2_bin, a2_bout
      p[20], p[22],          // f2_gb, f2_bb
      p[32], p[34],          // b3_b1, b3_b2
      p[36],                 // out_b
      ws, (float*)d_out, B);
}

// Round 8
// 217.927 us; speedup vs baseline: 1.6458x; 1.1291x over previous
//
#include <hip/hip_runtime.h>
#include <math.h>

typedef __attribute__((ext_vector_type(8))) short   short8;   // 8 fp16 bit-container (4 VGPRs)
typedef __attribute__((ext_vector_type(8))) _Float16 half8;
typedef __attribute__((ext_vector_type(2))) __fp16  fp16x2;   // cvt_pkrtz result type
typedef __attribute__((ext_vector_type(4))) float   f32x4;    // MFMA C/D frag

__device__ __forceinline__ half8 as_h8(short8 s) {
  union { short8 s; half8 h; } u; u.s = s; return u.h;
}
#define MFMA16(a,b,c) __builtin_amdgcn_mfma_f32_16x16x32_f16(as_h8(a), as_h8(b), (c), 0, 0, 0)

// ---- ws layout: 164 frag-blocks of 1024 B (64 lanes x 16 B) ----
#define WS_B1W1   0
#define WS_B1W2   12
#define WS_LPW1   20
#define WS_LPW2   24
#define WS_A1WIN  28
#define WS_A1WOUT 52
#define WS_F1GW   60
#define WS_F1BW   68
#define WS_B2W1   76
#define WS_B2W2   84
#define WS_A2WIN  92
#define WS_A2WOUT 116
#define WS_F2GW   124
#define WS_F2BW   132
#define WS_B3W1   140
#define WS_B3W2   148
#define WS_OUTW   156
#define WS_FRAGS  164

// f32 -> fp16 (prep + scalar paths)
__device__ __forceinline__ unsigned short f2h(float f) {
  union { _Float16 h; unsigned short u; } r;
  r.h = (_Float16)f;
  return r.u;
}
// packed f32x2 -> fp16x2 (RTZ), single VALU op, standard clang builtin
__device__ __forceinline__ unsigned int pkrtz(float lo, float hi) {
  union { fp16x2 h; unsigned int u; } r;
  r.h = __builtin_amdgcn_cvt_pkrtz(lo, hi);
  return r.u;
}

__device__ __forceinline__ short8 pack8(float4 a, float4 b) {
  union { unsigned int u[4]; short8 s; } r;
  r.u[0] = pkrtz(a.x, a.y);
  r.u[1] = pkrtz(a.z, a.w);
  r.u[2] = pkrtz(b.x, b.y);
  r.u[3] = pkrtz(b.z, b.w);
  return r.s;
}

__device__ __forceinline__ short8 zero8() {
  short8 r;
  #pragma unroll
  for (int j = 0; j < 8; ++j) r[j] = 0;
  return r;
}

// exact fp16 sign flip (for k0-k1 accumulated in one MFMA chain)
__device__ __forceinline__ short8 neg8(short8 a) {
  union { short8 s; unsigned int u[4]; } r;
  r.s = a;
  #pragma unroll
  for (int i = 0; i < 4; ++i) r.u[i] ^= 0x80008000u;
  return r.s;
}

__device__ __forceinline__ f32x4 relu4(f32x4 v) {
  f32x4 r;
  #pragma unroll
  for (int j = 0; j < 4; ++j) r[j] = fmaxf(v[j], 0.0f);
  return r;
}

// ============ prep: weights f32 -> fp16 B-fragments in d_ws ============
// B-frag layout (16x16x32): lane l holds B[k = (l>>4)*8 + j][col = l&15], j=0..7.
__global__ __launch_bounds__(64) void prep_kernel(
    const float* b1w1, const float* b1w2, const float* lpw1, const float* lpw2,
    const float* a1win, const float* a1wout, const float* f1gw, const float* f1bw,
    const float* b2w1, const float* b2w2, const float* a2win, const float* a2wout,
    const float* f2gw, const float* f2bw, const float* b3w1, const float* b3w2,
    const float* outw, unsigned short* ws)
{
  const float* WS_[17] = {b1w1,b1w2,lpw1,lpw2,a1win,a1wout,f1gw,f1bw,b2w1,b2w2,
                          a2win,a2wout,f2gw,f2bw,b3w1,b3w2,outw};
  const int KA[17] = {80,64,40,32,64,64,64,64,64,64,64,64,64,64,64,64,64};
  const int NA[17] = {64,64,32,64,192,64,64,64,64,64,192,64,64,64,64,64,64};
  const int FO[17] = {0,12,20,24,28,52,60,68,76,84,92,116,124,132,140,148,156};

  const int b = blockIdx.x;
  int m = 0;
  #pragma unroll
  for (int i = 1; i < 17; ++i) if (b >= FO[i]) m = i;
  const int f  = b - FO[m];
  const int K  = KA[m], N = NA[m];
  const int kc = (K + 31) >> 5;
  const int n  = f / kc, c = f % kc;

  const int lane = threadIdx.x;
  const int col  = n * 16 + (lane & 15);
  const int kb   = c * 32 + ((lane >> 4) * 8);
  const float* W = WS_[m];

  short8 r;
  #pragma unroll
  for (int j = 0; j < 8; ++j) {
    const int k = kb + j;
    const float v = (k < K) ? W[(size_t)k * N + col] : 0.0f;
    r[j] = (short)f2h(v);
  }
  *reinterpret_cast<short8*>(ws + (size_t)b * 512 + lane * 8) = r;
}

// ============ main kernel helpers ============
// Per-wave LDS: 2 sub-tiles of 16 rows x stride 72 fp16 (1152 ushort each).
__device__ __forceinline__ short8 ldA(const unsigned short* Ab, int c) {
  return *reinterpret_cast<const short8*>(Ab + c * 32);
}
__device__ __forceinline__ void stC(unsigned short* Cb, int n, f32x4 v) {
  const unsigned int p01 = pkrtz(v[0], v[1]);
  const unsigned int p23 = pkrtz(v[2], v[3]);
  unsigned short* p = Cb + n * 16;
  p[0]   = (unsigned short)p01;
  p[72]  = (unsigned short)(p01 >> 16);   // ds_write_b16_d16_hi
  p[144] = (unsigned short)p23;
  p[216] = (unsigned short)(p23 >> 16);
}
// sum over 16-lane groups, broadcast
__device__ __forceinline__ float rowsum16(float v) {
  v += __shfl_xor(v, 1);
  v += __shfl_xor(v, 2);
  v += __shfl_xor(v, 4);
  v += __shfl_xor(v, 8);
  return v;
}

// ============ main kernel: 4 waves/block, 32 rows/wave (2 independent 16-row chains) ============
__global__ __launch_bounds__(256, 4) void flow_mfma(
    const float* __restrict__ x, const float* __restrict__ t, const float* __restrict__ y,
    const float* __restrict__ b1b1, const float* __restrict__ b1b2,
    const float* __restrict__ lpb1, const float* __restrict__ lpb2,
    const float* __restrict__ a1bin, const float* __restrict__ a1bout,
    const float* __restrict__ f1gb, const float* __restrict__ f1bb,
    const float* __restrict__ b2b1, const float* __restrict__ b2b2,
    const float* __restrict__ a2bin, const float* __restrict__ a2bout,
    const float* __restrict__ f2gb, const float* __restrict__ f2bb,
    const float* __restrict__ b3b1, const float* __restrict__ b3b2,
    const float* __restrict__ outb,
    const unsigned short* __restrict__ ws,
    float* __restrict__ out, int Btotal)
{
  __shared__ __align__(16) unsigned short lds[4][2 * 16 * 72];
  const int tid  = threadIdx.x;
  const int lane = tid & 63, wid = tid >> 6;
  const int lrow = lane & 15, grp = lane >> 4;
  const int r0   = (blockIdx.x * 4 + wid) * 32;
  if (r0 >= Btotal) return;
  unsigned short* T = &lds[wid][0];
  unsigned short* Ab[2];
  unsigned short* Cb[2];
  #pragma unroll
  for (int u = 0; u < 2; ++u) {
    Ab[u] = T + u * 1152 + lrow * 72 + grp * 8;   // A-frag read base
    Cb[u] = T + u * 1152 + grp * 288 + lrow;      // C-frag write base
  }
  const short8* wsl = reinterpret_cast<const short8*>(ws) + lane;

  // ---- h80 A-frags: x (chunks 0,1) + time features (chunk 2, zero-padded 80..95)
  short8 hA0[2], hA1[2], hA2[2];
  #pragma unroll
  for (int u = 0; u < 2; ++u) {
    const size_t row = (size_t)r0 + u * 16 + lrow;
    const float4* xp = reinterpret_cast<const float4*>(x + row * 64) + grp * 2;
    hA0[u] = pack8(xp[0], xp[1]);
    hA1[u] = pack8(xp[8], xp[9]);
    const float tv = t[row];
    // sin/cos(pi*t*2^j) by double-angle recursion from one libm pair.
    float s = sinf(3.14159265358979323846f * tv);
    float c = cosf(3.14159265358979323846f * tv);
    short8 hp;
    #pragma unroll
    for (int j = 0; j < 8; ++j) {
      const float v = (grp == 0) ? s : ((grp == 1) ? c : 0.0f);
      hp[j] = (short)f2h(v);
      const float s2 = 2.0f * s * c;
      const float c2 = 1.0f - 2.0f * s * s;
      s = s2; c = c2;
    }
    hA2[u] = hp;
  }

  // ---- block1: h = relu(h80@b1_w1+b1) @ b1_w2 + b2
  #pragma unroll
  for (int n = 0; n < 4; ++n) {
    const short8 B0 = wsl[(WS_B1W1 + n * 3 + 0) * 64];
    const short8 B1 = wsl[(WS_B1W1 + n * 3 + 1) * 64];
    const short8 B2 = wsl[(WS_B1W1 + n * 3 + 2) * 64];
    const float bias = b1b1[n * 16 + lrow];
    #pragma unroll
    for (int u = 0; u < 2; ++u) {
      f32x4 acc = {bias, bias, bias, bias};
      acc = MFMA16(hA0[u], B0, acc);
      acc = MFMA16(hA1[u], B1, acc);
      acc = MFMA16(hA2[u], B2, acc);
      stC(Cb[u], n, relu4(acc));
    }
  }
  #pragma unroll
  for (int u = 0; u < 2; ++u) { hA0[u] = ldA(Ab[u], 0); hA1[u] = ldA(Ab[u], 1); }
  #pragma unroll
  for (int n = 0; n < 4; ++n) {
    const short8 B0 = wsl[(WS_B1W2 + n * 2 + 0) * 64];
    const short8 B1 = wsl[(WS_B1W2 + n * 2 + 1) * 64];
    const float bias = b1b2[n * 16 + lrow];
    #pragma unroll
    for (int u = 0; u < 2; ++u) {
      f32x4 acc = {bias, bias, bias, bias};
      acc = MFMA16(hA0[u], B0, acc);
      acc = MFMA16(hA1[u], B1, acc);
      stC(Cb[u], n, acc);
    }
  }
  #pragma unroll
  for (int u = 0; u < 2; ++u) { hA0[u] = ldA(Ab[u], 0); hA1[u] = ldA(Ab[u], 1); }

  // ---- label projection: ye = relu(y@lp_w1+b1) @ lp_w2 + b2
  short8 yeA0[2], yeA1[2];
  {
    short8 y0[2], y1[2];
    #pragma unroll
    for (int u = 0; u < 2; ++u) {
      const float* yrow = y + ((size_t)r0 + u * 16 + lrow) * 40;
      y0[u] = pack8(*reinterpret_cast<const float4*>(yrow + grp * 8),
                    *reinterpret_cast<const float4*>(yrow + grp * 8 + 4));
      y1[u] = (grp == 0) ? pack8(*reinterpret_cast<const float4*>(yrow + 32),
                                 *reinterpret_cast<const float4*>(yrow + 36))
                         : zero8();
    }
    #pragma unroll
    for (int n = 0; n < 2; ++n) {
      const short8 B0 = wsl[(WS_LPW1 + n * 2 + 0) * 64];
      const short8 B1 = wsl[(WS_LPW1 + n * 2 + 1) * 64];
      const float bias = lpb1[n * 16 + lrow];
      #pragma unroll
      for (int u = 0; u < 2; ++u) {
        f32x4 acc = {bias, bias, bias, bias};
        acc = MFMA16(y0[u], B0, acc);
        acc = MFMA16(y1[u], B1, acc);
        stC(Cb[u], n, relu4(acc));
      }
    }
    short8 z[2];
    #pragma unroll
    for (int u = 0; u < 2; ++u) z[u] = ldA(Ab[u], 0);
    #pragma unroll
    for (int n = 0; n < 4; ++n) {
      const short8 B0 = wsl[(WS_LPW2 + n) * 64];
      const float bias = lpb2[n * 16 + lrow];
      #pragma unroll
      for (int u = 0; u < 2; ++u)
        stC(Cb[u], n, MFMA16(z[u], B0, ((f32x4){bias, bias, bias, bias})));
    }
    #pragma unroll
    for (int u = 0; u < 2; ++u) { yeA0[u] = ldA(Ab[u], 0); yeA1[u] = ldA(Ab[u], 1); }
  }

  // ---- two reps of [attention -> FiLM -> residual block]
  f32x4 hC[4][2];              // C-form f32 copy of current h (for residual); all indices unrolled
  #pragma unroll 1
  for (int rep = 0; rep < 2; ++rep) {
    const int WIN  = rep ? WS_A2WIN  : WS_A1WIN;
    const int WOUT = rep ? WS_A2WOUT : WS_A1WOUT;
    const int GW   = rep ? WS_F2GW   : WS_F1GW;
    const int BW   = rep ? WS_F2BW   : WS_F1BW;
    const int W1   = rep ? WS_B3W1   : WS_B2W1;
    const int W2   = rep ? WS_B3W2   : WS_B2W2;
    const float* binp  = rep ? a2bin  : a1bin;
    const float* boutp = rep ? a2bout : a1bout;
    const float* gbp   = rep ? f2gb   : f1gb;
    const float* fbp   = rep ? f2bb   : f1bb;
    const float* w1b   = rep ? b3b1   : b2b1;
    const float* w2b   = rep ? b3b2   : b2b2;

    // attention per head n. p0 = sigmoid(0.25*q.(k0-k1)); o = v1 + p0*(v0-v1).
    #pragma unroll 1
    for (int n = 0; n < 4; ++n) {
      const short8 Bq0 = wsl[(WIN + n * 2 + 0) * 64];
      const short8 Bq1 = wsl[(WIN + n * 2 + 1) * 64];
      const short8 Bk0 = wsl[(WIN + (4 + n) * 2 + 0) * 64];
      const short8 Bk1 = wsl[(WIN + (4 + n) * 2 + 1) * 64];
      const short8 Bv0 = wsl[(WIN + (8 + n) * 2 + 0) * 64];
      const short8 Bv1 = wsl[(WIN + (8 + n) * 2 + 1) * 64];
      const float bq = binp[n * 16 + lrow];
      const float bv = binp[128 + n * 16 + lrow];
      #pragma unroll
      for (int u = 0; u < 2; ++u) {
        f32x4 q = {bq, bq, bq, bq};
        q = MFMA16(hA0[u], Bq0, q);
        q = MFMA16(hA1[u], Bq1, q);
        f32x4 kd = {0.0f, 0.0f, 0.0f, 0.0f};
        kd = MFMA16(hA0[u], Bk0, kd);
        kd = MFMA16(hA1[u], Bk1, kd);
        kd = MFMA16(neg8(yeA0[u]), Bk0, kd);   // bias cancels in k0-k1
        kd = MFMA16(neg8(yeA1[u]), Bk1, kd);
        f32x4 v0 = {bv, bv, bv, bv}, v1 = {bv, bv, bv, bv};
        v0 = MFMA16(hA0[u],  Bv0, v0);
        v0 = MFMA16(hA1[u],  Bv1, v0);
        v1 = MFMA16(yeA0[u], Bv0, v1);
        v1 = MFMA16(yeA1[u], Bv1, v1);
        f32x4 ov;
        #pragma unroll
        for (int j = 0; j < 4; ++j) {
          const float d = rowsum16(q[j] * kd[j]);
          const float p0 = 1.0f / (1.0f + __expf(-0.25f * d));
          ov[j] = fmaf(p0, v0[j] - v1[j], v1[j]);
        }
        stC(Cb[u], n, ov);
      }
    }
    #pragma unroll
    for (int u = 0; u < 2; ++u) { hA0[u] = ldA(Ab[u], 0); hA1[u] = ldA(Ab[u], 1); }  // attn out

    // out-proj + FiLM fused per tile; hC kept in regs (all loops unrolled)
    #pragma unroll
    for (int n = 0; n < 4; ++n) {
      const short8 Bo0 = wsl[(WOUT + n * 2 + 0) * 64];
      const short8 Bo1 = wsl[(WOUT + n * 2 + 1) * 64];
      const short8 Bg0 = wsl[(GW + n * 2 + 0) * 64];
      const short8 Bg1 = wsl[(GW + n * 2 + 1) * 64];
      const short8 Bb0 = wsl[(BW + n * 2 + 0) * 64];
      const short8 Bb1 = wsl[(BW + n * 2 + 1) * 64];
      const float bo = boutp[n * 16 + lrow];
      const float bg = gbp[n * 16 + lrow];
      const float bf = fbp[n * 16 + lrow];
      #pragma unroll
      for (int u = 0; u < 2; ++u) {
        f32x4 at = {bo, bo, bo, bo};
        at = MFMA16(hA0[u], Bo0, at);
        at = MFMA16(hA1[u], Bo1, at);
        f32x4 g = {bg, bg, bg, bg};
        g = MFMA16(yeA0[u], Bg0, g);
        g = MFMA16(yeA1[u], Bg1, g);
        f32x4 fb = {bf, bf, bf, bf};
        fb = MFMA16(yeA0[u], Bb0, fb);
        fb = MFMA16(yeA1[u], Bb1, fb);
        f32x4 hv;
        #pragma unroll
        for (int j = 0; j < 4; ++j) hv[j] = fmaf(g[j], at[j], fb[j]);
        hC[n][u] = hv;
        stC(Cb[u], n, hv);
      }
    }
    #pragma unroll
    for (int u = 0; u < 2; ++u) { hA0[u] = ldA(Ab[u], 0); hA1[u] = ldA(Ab[u], 1); }  // FiLM out

    // residual block: h = h + relu(h@w1+b1) @ w2 + b2
    #pragma unroll
    for (int n = 0; n < 4; ++n) {
      const short8 B0 = wsl[(W1 + n * 2 + 0) * 64];
      const short8 B1 = wsl[(W1 + n * 2 + 1) * 64];
      const float bias = w1b[n * 16 + lrow];
      #pragma unroll
      for (int u = 0; u < 2; ++u) {
        f32x4 acc = {bias, bias, bias, bias};
        acc = MFMA16(hA0[u], B0, acc);
        acc = MFMA16(hA1[u], B1, acc);
        stC(Cb[u], n, relu4(acc));
      }
    }
    #pragma unroll
    for (int u = 0; u < 2; ++u) { hA0[u] = ldA(Ab[u], 0); hA1[u] = ldA(Ab[u], 1); }  // u (hidden)
    #pragma unroll
    for (int n = 0; n < 4; ++n) {
      const short8 B0 = wsl[(W2 + n * 2 + 0) * 64];
      const short8 B1 = wsl[(W2 + n * 2 + 1) * 64];
      const float bias = w2b[n * 16 + lrow];
      #pragma unroll
      for (int u = 0; u < 2; ++u) {
        f32x4 acc = {bias, bias, bias, bias};
        acc = MFMA16(hA0[u], B0, acc);
        acc = MFMA16(hA1[u], B1, acc);
        #pragma unroll
        for (int j = 0; j < 4; ++j) acc[j] += hC[n][u][j];
        stC(Cb[u], n, acc);
      }
    }
    #pragma unroll
    for (int u = 0; u < 2; ++u) { hA0[u] = ldA(Ab[u], 0); hA1[u] = ldA(Ab[u], 1); }  // next h
  }

  // ---- final projection + store (f32, coalesced 64B per 16-lane group)
  #pragma unroll 1
  for (int n = 0; n < 4; ++n) {
    const short8 B0 = wsl[(WS_OUTW + n * 2 + 0) * 64];
    const short8 B1 = wsl[(WS_OUTW + n * 2 + 1) * 64];
    const float bias = outb[n * 16 + lrow];
    #pragma unroll
    for (int u = 0; u < 2; ++u) {
      f32x4 a = {bias, bias, bias, bias};
      a = MFMA16(hA0[u], B0, a);
      a = MFMA16(hA1[u], B1, a);
      float* ob = out + ((size_t)r0 + u * 16 + grp * 4) * 64 + n * 16 + lrow;
      #pragma unroll
      for (int j = 0; j < 4; ++j)
        ob[j * 64] = a[j];
    }
  }
}

extern "C" void kernel_launch(void* const* d_in, const int* in_sizes, int n_in,
                              void* d_out, int out_size, void* d_ws, size_t ws_size,
                              hipStream_t stream) {
  (void)n_in; (void)out_size; (void)ws_size;
  const float* p[37];
  for (int i = 0; i < 37; ++i) p[i] = (const float*)d_in[i];
  unsigned short* ws = (unsigned short*)d_ws;

  prep_kernel<<<dim3(WS_FRAGS), dim3(64), 0, stream>>>(
      p[23], p[25], p[3], p[5], p[7], p[9], p[15], p[17],
      p[27], p[29], p[11], p[13], p[19], p[21], p[31], p[33], p[35], ws);

  const int B = in_sizes[0] / 64;
  const int grid = (B + 127) / 128;   // 128 rows per block (4 waves x 32)
  flow_mfma<<<dim3(grid), dim3(256), 0, stream>>>(
      p[0], p[1], p[2],
      p[24], p[26],          // b1_b1, b1_b2
      p[4],  p[6],           // lp_b1, lp_b2
      p[8],  p[10],          // a1_bin, a1_bout
      p[16], p[18],          // f1_gb, f1_bb
      p[28], p[30],          // b2_b1, b2_b2
      p[12], p[14],          // a2_bin, a2_bout
      p[20], p[22],          // f2_gb, f2_bb
      p[32], p[34],          // b3_b1, b3_b2
      p[36],                 // out_b
      ws, (float*)d_out, B);
}

// Round 9
// 203.171 us; speedup vs baseline: 1.7653x; 1.0726x over previous
//
#include <hip/hip_runtime.h>
#include <math.h>

typedef __attribute__((ext_vector_type(8))) short   short8;   // 8 fp16 bit-container (4 VGPRs)
typedef __attribute__((ext_vector_type(8))) _Float16 half8;
typedef __attribute__((ext_vector_type(2))) __fp16  fp16x2;   // cvt_pkrtz result type
typedef __attribute__((ext_vector_type(4))) float   f32x4;    // MFMA C/D frag

__device__ __forceinline__ half8 as_h8(short8 s) {
  union { short8 s; half8 h; } u; u.s = s; return u.h;
}
#define MFMA16(a,b,c) __builtin_amdgcn_mfma_f32_16x16x32_f16(as_h8(a), as_h8(b), (c), 0, 0, 0)

// ---- ws layout: 164 frag-blocks of 1024 B (64 lanes x 16 B) ----
#define WS_B1W1   0
#define WS_B1W2   12
#define WS_LPW1   20
#define WS_LPW2   24
#define WS_A1WIN  28
#define WS_A1WOUT 52
#define WS_F1GW   60
#define WS_F1BW   68
#define WS_B2W1   76
#define WS_B2W2   84
#define WS_A2WIN  92
#define WS_A2WOUT 116
#define WS_F2GW   124
#define WS_F2BW   132
#define WS_B3W1   140
#define WS_B3W2   148
#define WS_OUTW   156
#define WS_FRAGS  164

// f32 -> fp16 (prep + scalar paths)
__device__ __forceinline__ unsigned short f2h(float f) {
  union { _Float16 h; unsigned short u; } r;
  r.h = (_Float16)f;
  return r.u;
}
// packed f32x2 -> fp16x2 (RTZ), single VALU op
__device__ __forceinline__ unsigned int pkrtz(float lo, float hi) {
  union { fp16x2 h; unsigned int u; } r;
  r.h = __builtin_amdgcn_cvt_pkrtz(lo, hi);
  return r.u;
}
// unpack fp16 halves of a uint -> f32 (v_cvt_f32_f16)
__device__ __forceinline__ float h_lo(unsigned int p) {
  union { unsigned short s; _Float16 h; } c; c.s = (unsigned short)p; return (float)c.h;
}
__device__ __forceinline__ float h_hi(unsigned int p) {
  union { unsigned short s; _Float16 h; } c; c.s = (unsigned short)(p >> 16); return (float)c.h;
}

__device__ __forceinline__ short8 pack8(float4 a, float4 b) {
  union { unsigned int u[4]; short8 s; } r;
  r.u[0] = pkrtz(a.x, a.y);
  r.u[1] = pkrtz(a.z, a.w);
  r.u[2] = pkrtz(b.x, b.y);
  r.u[3] = pkrtz(b.z, b.w);
  return r.s;
}

__device__ __forceinline__ short8 zero8() {
  short8 r;
  #pragma unroll
  for (int j = 0; j < 8; ++j) r[j] = 0;
  return r;
}

// exact fp16 sign flip (for k0-k1 accumulated in one MFMA chain)
__device__ __forceinline__ short8 neg8(short8 a) {
  union { short8 s; unsigned int u[4]; } r;
  r.s = a;
  #pragma unroll
  for (int i = 0; i < 4; ++i) r.u[i] ^= 0x80008000u;
  return r.s;
}

__device__ __forceinline__ f32x4 relu4(f32x4 v) {
  f32x4 r;
  #pragma unroll
  for (int j = 0; j < 4; ++j) r[j] = fmaxf(v[j], 0.0f);
  return r;
}

// ============ prep: weights f32 -> fp16 B-fragments in d_ws ============
// B-frag layout (16x16x32): lane l holds B[k = (l>>4)*8 + j][col = l&15], j=0..7.
__global__ __launch_bounds__(64) void prep_kernel(
    const float* b1w1, const float* b1w2, const float* lpw1, const float* lpw2,
    const float* a1win, const float* a1wout, const float* f1gw, const float* f1bw,
    const float* b2w1, const float* b2w2, const float* a2win, const float* a2wout,
    const float* f2gw, const float* f2bw, const float* b3w1, const float* b3w2,
    const float* outw, unsigned short* ws)
{
  const float* WS_[17] = {b1w1,b1w2,lpw1,lpw2,a1win,a1wout,f1gw,f1bw,b2w1,b2w2,
                          a2win,a2wout,f2gw,f2bw,b3w1,b3w2,outw};
  const int KA[17] = {80,64,40,32,64,64,64,64,64,64,64,64,64,64,64,64,64};
  const int NA[17] = {64,64,32,64,192,64,64,64,64,64,192,64,64,64,64,64,64};
  const int FO[17] = {0,12,20,24,28,52,60,68,76,84,92,116,124,132,140,148,156};

  const int b = blockIdx.x;
  int m = 0;
  #pragma unroll
  for (int i = 1; i < 17; ++i) if (b >= FO[i]) m = i;
  const int f  = b - FO[m];
  const int K  = KA[m], N = NA[m];
  const int kc = (K + 31) >> 5;
  const int n  = f / kc, c = f % kc;

  const int lane = threadIdx.x;
  const int col  = n * 16 + (lane & 15);
  const int kb   = c * 32 + ((lane >> 4) * 8);
  const float* W = WS_[m];

  short8 r;
  #pragma unroll
  for (int j = 0; j < 8; ++j) {
    const int k = kb + j;
    const float v = (k < K) ? W[(size_t)k * N + col] : 0.0f;
    r[j] = (short)f2h(v);
  }
  *reinterpret_cast<short8*>(ws + (size_t)b * 512 + lane * 8) = r;
}

// ============ main kernel helpers ============
// Per-wave LDS: 2 sub-tiles of 16 rows x stride 72 fp16 (1152 ushort each).
__device__ __forceinline__ short8 ldA(const unsigned short* Ab, int c) {
  return *reinterpret_cast<const short8*>(Ab + c * 32);
}
__device__ __forceinline__ void stC_pk(unsigned short* Cb, int n, unsigned int p01, unsigned int p23) {
  unsigned short* p = Cb + n * 16;
  p[0]   = (unsigned short)p01;
  p[72]  = (unsigned short)(p01 >> 16);   // ds_write_b16_d16_hi
  p[144] = (unsigned short)p23;
  p[216] = (unsigned short)(p23 >> 16);
}
__device__ __forceinline__ void stC(unsigned short* Cb, int n, f32x4 v) {
  stC_pk(Cb, n, pkrtz(v[0], v[1]), pkrtz(v[2], v[3]));
}
// sum over 16-lane groups, broadcast
__device__ __forceinline__ float rowsum16(float v) {
  v += __shfl_xor(v, 1);
  v += __shfl_xor(v, 2);
  v += __shfl_xor(v, 4);
  v += __shfl_xor(v, 8);
  return v;
}

// ============ main kernel: 4 waves/block, 32 rows/wave (2 independent 16-row chains) ============
__global__ __launch_bounds__(256, 4) void flow_mfma(
    const float* __restrict__ x, const float* __restrict__ t, const float* __restrict__ y,
    const float* __restrict__ b1b1, const float* __restrict__ b1b2,
    const float* __restrict__ lpb1, const float* __restrict__ lpb2,
    const float* __restrict__ a1bin, const float* __restrict__ a1bout,
    const float* __restrict__ f1gb, const float* __restrict__ f1bb,
    const float* __restrict__ b2b1, const float* __restrict__ b2b2,
    const float* __restrict__ a2bin, const float* __restrict__ a2bout,
    const float* __restrict__ f2gb, const float* __restrict__ f2bb,
    const float* __restrict__ b3b1, const float* __restrict__ b3b2,
    const float* __restrict__ outb,
    const unsigned short* __restrict__ ws,
    float* __restrict__ out, int Btotal)
{
  __shared__ __align__(16) unsigned short lds[4][2 * 16 * 72];
  const int tid  = threadIdx.x;
  const int lane = tid & 63, wid = tid >> 6;
  const int lrow = lane & 15, grp = lane >> 4;
  const int r0   = (blockIdx.x * 4 + wid) * 32;
  if (r0 >= Btotal) return;
  unsigned short* T = &lds[wid][0];
  unsigned short* Ab[2];
  unsigned short* Cb[2];
  #pragma unroll
  for (int u = 0; u < 2; ++u) {
    Ab[u] = T + u * 1152 + lrow * 72 + grp * 8;   // A-frag read base
    Cb[u] = T + u * 1152 + grp * 288 + lrow;      // C-frag write base
  }
  const short8* wsl = reinterpret_cast<const short8*>(ws) + lane;

  // ---- h80 A-frags: x (chunks 0,1) + time features (chunk 2, zero-padded 80..95)
  short8 hA0[2], hA1[2];
  {
    short8 tF[2];
    #pragma unroll
    for (int u = 0; u < 2; ++u) {
      const size_t row = (size_t)r0 + u * 16 + lrow;
      const float4* xp = reinterpret_cast<const float4*>(x + row * 64) + grp * 2;
      hA0[u] = pack8(xp[0], xp[1]);
      hA1[u] = pack8(xp[8], xp[9]);
      const float tv = t[row];
      float s = sinf(3.14159265358979323846f * tv);
      float c = cosf(3.14159265358979323846f * tv);
      short8 hp;
      #pragma unroll
      for (int j = 0; j < 8; ++j) {
        const float v = (grp == 0) ? s : ((grp == 1) ? c : 0.0f);
        hp[j] = (short)f2h(v);
        const float s2 = 2.0f * s * c;
        const float c2 = 1.0f - 2.0f * s * s;
        s = s2; c = c2;
      }
      tF[u] = hp;
    }
    // block1 w1 (K=80, ReLU)
    #pragma unroll
    for (int n = 0; n < 4; ++n) {
      const short8 B0 = wsl[(WS_B1W1 + n * 3 + 0) * 64];
      const short8 B1 = wsl[(WS_B1W1 + n * 3 + 1) * 64];
      const short8 B2 = wsl[(WS_B1W1 + n * 3 + 2) * 64];
      const float bias = b1b1[n * 16 + lrow];
      #pragma unroll
      for (int u = 0; u < 2; ++u) {
        f32x4 acc = {bias, bias, bias, bias};
        acc = MFMA16(hA0[u], B0, acc);
        acc = MFMA16(hA1[u], B1, acc);
        acc = MFMA16(tF[u],  B2, acc);
        stC(Cb[u], n, relu4(acc));
      }
    }
  }
  #pragma unroll
  for (int u = 0; u < 2; ++u) { hA0[u] = ldA(Ab[u], 0); hA1[u] = ldA(Ab[u], 1); }
  #pragma unroll
  for (int n = 0; n < 4; ++n) {
    const short8 B0 = wsl[(WS_B1W2 + n * 2 + 0) * 64];
    const short8 B1 = wsl[(WS_B1W2 + n * 2 + 1) * 64];
    const float bias = b1b2[n * 16 + lrow];
    #pragma unroll
    for (int u = 0; u < 2; ++u) {
      f32x4 acc = {bias, bias, bias, bias};
      acc = MFMA16(hA0[u], B0, acc);
      acc = MFMA16(hA1[u], B1, acc);
      stC(Cb[u], n, acc);
    }
  }
  #pragma unroll
  for (int u = 0; u < 2; ++u) { hA0[u] = ldA(Ab[u], 0); hA1[u] = ldA(Ab[u], 1); }

  // ---- label projection: ye = relu(y@lp_w1+b1) @ lp_w2 + b2
  short8 yeA0[2], yeA1[2];
  {
    short8 y0[2], y1[2];
    #pragma unroll
    for (int u = 0; u < 2; ++u) {
      const float* yrow = y + ((size_t)r0 + u * 16 + lrow) * 40;
      y0[u] = pack8(*reinterpret_cast<const float4*>(yrow + grp * 8),
                    *reinterpret_cast<const float4*>(yrow + grp * 8 + 4));
      y1[u] = (grp == 0) ? pack8(*reinterpret_cast<const float4*>(yrow + 32),
                                 *reinterpret_cast<const float4*>(yrow + 36))
                         : zero8();
    }
    #pragma unroll
    for (int n = 0; n < 2; ++n) {
      const short8 B0 = wsl[(WS_LPW1 + n * 2 + 0) * 64];
      const short8 B1 = wsl[(WS_LPW1 + n * 2 + 1) * 64];
      const float bias = lpb1[n * 16 + lrow];
      #pragma unroll
      for (int u = 0; u < 2; ++u) {
        f32x4 acc = {bias, bias, bias, bias};
        acc = MFMA16(y0[u], B0, acc);
        acc = MFMA16(y1[u], B1, acc);
        stC(Cb[u], n, relu4(acc));
      }
    }
    short8 z[2];
    #pragma unroll
    for (int u = 0; u < 2; ++u) z[u] = ldA(Ab[u], 0);
    #pragma unroll
    for (int n = 0; n < 4; ++n) {
      const short8 B0 = wsl[(WS_LPW2 + n) * 64];
      const float bias = lpb2[n * 16 + lrow];
      #pragma unroll
      for (int u = 0; u < 2; ++u)
        stC(Cb[u], n, MFMA16(z[u], B0, ((f32x4){bias, bias, bias, bias})));
    }
    #pragma unroll
    for (int u = 0; u < 2; ++u) { yeA0[u] = ldA(Ab[u], 0); yeA1[u] = ldA(Ab[u], 1); }
  }

  // ---- two reps of [attention -> FiLM -> residual block]
  // residual carry kept PACKED fp16 (2 uints per (n,u)) to save 16 VGPRs vs f32
  unsigned int hCp01[4][2], hCp23[4][2];
  #pragma unroll 1
  for (int rep = 0; rep < 2; ++rep) {
    const int WIN  = rep ? WS_A2WIN  : WS_A1WIN;
    const int WOUT = rep ? WS_A2WOUT : WS_A1WOUT;
    const int GW   = rep ? WS_F2GW   : WS_F1GW;
    const int BW   = rep ? WS_F2BW   : WS_F1BW;
    const int W1   = rep ? WS_B3W1   : WS_B2W1;
    const int W2   = rep ? WS_B3W2   : WS_B2W2;
    const float* binp  = rep ? a2bin  : a1bin;
    const float* boutp = rep ? a2bout : a1bout;
    const float* gbp   = rep ? f2gb   : f1gb;
    const float* fbp   = rep ? f2bb   : f1bb;
    const float* w1b   = rep ? b3b1   : b2b1;
    const float* w2b   = rep ? b3b2   : b2b2;

    // attention per head n. Phase 1: q,kd (frags Bq,Bk); phase 2: v (frags Bv).
    #pragma unroll 1
    for (int n = 0; n < 4; ++n) {
      float pr[2][4];
      {
        const short8 Bq0 = wsl[(WIN + n * 2 + 0) * 64];
        const short8 Bq1 = wsl[(WIN + n * 2 + 1) * 64];
        const short8 Bk0 = wsl[(WIN + (4 + n) * 2 + 0) * 64];
        const short8 Bk1 = wsl[(WIN + (4 + n) * 2 + 1) * 64];
        const float bq = binp[n * 16 + lrow];
        #pragma unroll
        for (int u = 0; u < 2; ++u) {
          f32x4 q = {bq, bq, bq, bq};
          q = MFMA16(hA0[u], Bq0, q);
          q = MFMA16(hA1[u], Bq1, q);
          f32x4 kd = {0.0f, 0.0f, 0.0f, 0.0f};
          kd = MFMA16(hA0[u], Bk0, kd);
          kd = MFMA16(hA1[u], Bk1, kd);
          kd = MFMA16(neg8(yeA0[u]), Bk0, kd);   // bias cancels in k0-k1
          kd = MFMA16(neg8(yeA1[u]), Bk1, kd);
          #pragma unroll
          for (int j = 0; j < 4; ++j) {
            const float d = rowsum16(q[j] * kd[j]);
            pr[u][j] = 1.0f / (1.0f + __expf(-0.25f * d));
          }
        }
      }
      {
        const short8 Bv0 = wsl[(WIN + (8 + n) * 2 + 0) * 64];
        const short8 Bv1 = wsl[(WIN + (8 + n) * 2 + 1) * 64];
        const float bv = binp[128 + n * 16 + lrow];
        #pragma unroll
        for (int u = 0; u < 2; ++u) {
          f32x4 v0 = {bv, bv, bv, bv}, v1 = {bv, bv, bv, bv};
          v0 = MFMA16(hA0[u],  Bv0, v0);
          v0 = MFMA16(hA1[u],  Bv1, v0);
          v1 = MFMA16(yeA0[u], Bv0, v1);
          v1 = MFMA16(yeA1[u], Bv1, v1);
          f32x4 ov;
          #pragma unroll
          for (int j = 0; j < 4; ++j) ov[j] = fmaf(pr[u][j], v0[j] - v1[j], v1[j]);
          stC(Cb[u], n, ov);
        }
      }
    }
    #pragma unroll
    for (int u = 0; u < 2; ++u) { hA0[u] = ldA(Ab[u], 0); hA1[u] = ldA(Ab[u], 1); }  // attn out

    // out-proj + FiLM; sequenced frag lifetimes (at -> g -> fb), carry packed fp16
    #pragma unroll
    for (int n = 0; n < 4; ++n) {
      f32x4 at[2], g[2];
      {
        const short8 Bo0 = wsl[(WOUT + n * 2 + 0) * 64];
        const short8 Bo1 = wsl[(WOUT + n * 2 + 1) * 64];
        const float bo = boutp[n * 16 + lrow];
        #pragma unroll
        for (int u = 0; u < 2; ++u) {
          at[u] = (f32x4){bo, bo, bo, bo};
          at[u] = MFMA16(hA0[u], Bo0, at[u]);
          at[u] = MFMA16(hA1[u], Bo1, at[u]);
        }
      }
      {
        const short8 Bg0 = wsl[(GW + n * 2 + 0) * 64];
        const short8 Bg1 = wsl[(GW + n * 2 + 1) * 64];
        const float bg = gbp[n * 16 + lrow];
        #pragma unroll
        for (int u = 0; u < 2; ++u) {
          g[u] = (f32x4){bg, bg, bg, bg};
          g[u] = MFMA16(yeA0[u], Bg0, g[u]);
          g[u] = MFMA16(yeA1[u], Bg1, g[u]);
        }
      }
      {
        const short8 Bb0 = wsl[(BW + n * 2 + 0) * 64];
        const short8 Bb1 = wsl[(BW + n * 2 + 1) * 64];
        const float bf = fbp[n * 16 + lrow];
        #pragma unroll
        for (int u = 0; u < 2; ++u) {
          f32x4 fb = {bf, bf, bf, bf};
          fb = MFMA16(yeA0[u], Bb0, fb);
          fb = MFMA16(yeA1[u], Bb1, fb);
          f32x4 hv;
          #pragma unroll
          for (int j = 0; j < 4; ++j) hv[j] = fmaf(g[u][j], at[u][j], fb[j]);
          const unsigned int p01 = pkrtz(hv[0], hv[1]);
          const unsigned int p23 = pkrtz(hv[2], hv[3]);
          hCp01[n][u] = p01; hCp23[n][u] = p23;
          stC_pk(Cb[u], n, p01, p23);
        }
      }
    }
    #pragma unroll
    for (int u = 0; u < 2; ++u) { hA0[u] = ldA(Ab[u], 0); hA1[u] = ldA(Ab[u], 1); }  // FiLM out

    // residual block: h = h + relu(h@w1+b1) @ w2 + b2
    #pragma unroll
    for (int n = 0; n < 4; ++n) {
      const short8 B0 = wsl[(W1 + n * 2 + 0) * 64];
      const short8 B1 = wsl[(W1 + n * 2 + 1) * 64];
      const float bias = w1b[n * 16 + lrow];
      #pragma unroll
      for (int u = 0; u < 2; ++u) {
        f32x4 acc = {bias, bias, bias, bias};
        acc = MFMA16(hA0[u], B0, acc);
        acc = MFMA16(hA1[u], B1, acc);
        stC(Cb[u], n, relu4(acc));
      }
    }
    #pragma unroll
    for (int u = 0; u < 2; ++u) { hA0[u] = ldA(Ab[u], 0); hA1[u] = ldA(Ab[u], 1); }  // u (hidden)
    #pragma unroll
    for (int n = 0; n < 4; ++n) {
      const short8 B0 = wsl[(W2 + n * 2 + 0) * 64];
      const short8 B1 = wsl[(W2 + n * 2 + 1) * 64];
      const float bias = w2b[n * 16 + lrow];
      #pragma unroll
      for (int u = 0; u < 2; ++u) {
        f32x4 acc = {bias, bias, bias, bias};
        acc = MFMA16(hA0[u], B0, acc);
        acc = MFMA16(hA1[u], B1, acc);
        acc[0] += h_lo(hCp01[n][u]);
        acc[1] += h_hi(hCp01[n][u]);
        acc[2] += h_lo(hCp23[n][u]);
        acc[3] += h_hi(hCp23[n][u]);
        stC(Cb[u], n, acc);
      }
    }
    #pragma unroll
    for (int u = 0; u < 2; ++u) { hA0[u] = ldA(Ab[u], 0); hA1[u] = ldA(Ab[u], 1); }  // next h
  }

  // ---- final projection + store (f32, coalesced 64B per 16-lane group)
  #pragma unroll 1
  for (int n = 0; n < 4; ++n) {
    const short8 B0 = wsl[(WS_OUTW + n * 2 + 0) * 64];
    const short8 B1 = wsl[(WS_OUTW + n * 2 + 1) * 64];
    const float bias = outb[n * 16 + lrow];
    #pragma unroll
    for (int u = 0; u < 2; ++u) {
      f32x4 a = {bias, bias, bias, bias};
      a = MFMA16(hA0[u], B0, a);
      a = MFMA16(hA1[u], B1, a);
      float* ob = out + ((size_t)r0 + u * 16 + grp * 4) * 64 + n * 16 + lrow;
      #pragma unroll
      for (int j = 0; j < 4; ++j)
        ob[j * 64] = a[j];
    }
  }
}

extern "C" void kernel_launch(void* const* d_in, const int* in_sizes, int n_in,
                              void* d_out, int out_size, void* d_ws, size_t ws_size,
                              hipStream_t stream) {
  (void)n_in; (void)out_size; (void)ws_size;
  const float* p[37];
  for (int i = 0; i < 37; ++i) p[i] = (const float*)d_in[i];
  unsigned short* ws = (unsigned short*)d_ws;

  prep_kernel<<<dim3(WS_FRAGS), dim3(64), 0, stream>>>(
      p[23], p[25], p[3], p[5], p[7], p[9], p[15], p[17],
      p[27], p[29], p[11], p[13], p[19], p[21], p[31], p[33], p[35], ws);

  const int B = in_sizes[0] / 64;
  const int grid = (B + 127) / 128;   // 128 rows per block (4 waves x 32)
  flow_mfma<<<dim3(grid), dim3(256), 0, stream>>>(
      p[0], p[1], p[2],
      p[24], p[26],          // b1_b1, b1_b2
      p[4],  p[6],           // lp_b1, lp_b2
      p[8],  p[10],          // a1_bin, a1_bout
      p[16], p[18],          // f1_gb, f1_bb
      p[28], p[30],          // b2_b1, b2_b2
      p[12], p[14],          // a2_bin, a2_bout
      p[20], p[22],          // f2_gb, f2_bb
      p[32], p[34],          // b3_b1, b3_b2
      p[36],                 // out_b
      ws, (float*)d_out, B);
}

// Round 10
// 190.987 us; speedup vs baseline: 1.8779x; 1.0638x over previous
//
#include <hip/hip_runtime.h>
#include <math.h>

typedef __attribute__((ext_vector_type(8))) short   short8;   // 8 fp16 bit-container (4 VGPRs)
typedef __attribute__((ext_vector_type(8))) _Float16 half8;
typedef __attribute__((ext_vector_type(2))) __fp16  fp16x2;   // cvt_pkrtz result type
typedef __attribute__((ext_vector_type(4))) float   f32x4;    // MFMA C/D frag

__device__ __forceinline__ half8 as_h8(short8 s) {
  union { short8 s; half8 h; } u; u.s = s; return u.h;
}
#define MFMA16(a,b,c) __builtin_amdgcn_mfma_f32_16x16x32_f16(as_h8(a), as_h8(b), (c), 0, 0, 0)

// ---- ws layout: 164 frag-blocks of 1024 B (64 lanes x 16 B) ----
#define WS_B1W1   0
#define WS_B1W2   12
#define WS_LPW1   20
#define WS_LPW2   24
#define WS_A1WIN  28
#define WS_A1WOUT 52
#define WS_F1GW   60
#define WS_F1BW   68
#define WS_B2W1   76
#define WS_B2W2   84
#define WS_A2WIN  92
#define WS_A2WOUT 116
#define WS_F2GW   124
#define WS_F2BW   132
#define WS_B3W1   140
#define WS_B3W2   148
#define WS_OUTW   156
#define WS_FRAGS  164

// f32 -> fp16 (prep + scalar paths)
__device__ __forceinline__ unsigned short f2h(float f) {
  union { _Float16 h; unsigned short u; } r;
  r.h = (_Float16)f;
  return r.u;
}
// packed f32x2 -> fp16x2 (RTZ), single VALU op
__device__ __forceinline__ unsigned int pkrtz(float lo, float hi) {
  union { fp16x2 h; unsigned int u; } r;
  r.h = __builtin_amdgcn_cvt_pkrtz(lo, hi);
  return r.u;
}
// unpack fp16 halves of a uint -> f32 (v_cvt_f32_f16)
__device__ __forceinline__ float h_lo(unsigned int p) {
  union { unsigned short s; _Float16 h; } c; c.s = (unsigned short)p; return (float)c.h;
}
__device__ __forceinline__ float h_hi(unsigned int p) {
  union { unsigned short s; _Float16 h; } c; c.s = (unsigned short)(p >> 16); return (float)c.h;
}

__device__ __forceinline__ short8 pack8(float4 a, float4 b) {
  union { unsigned int u[4]; short8 s; } r;
  r.u[0] = pkrtz(a.x, a.y);
  r.u[1] = pkrtz(a.z, a.w);
  r.u[2] = pkrtz(b.x, b.y);
  r.u[3] = pkrtz(b.z, b.w);
  return r.s;
}

__device__ __forceinline__ short8 zero8() {
  short8 r;
  #pragma unroll
  for (int j = 0; j < 8; ++j) r[j] = 0;
  return r;
}

// exact fp16 sign flip (for k0-k1 accumulated in one MFMA chain)
__device__ __forceinline__ short8 neg8(short8 a) {
  union { short8 s; unsigned int u[4]; } r;
  r.s = a;
  #pragma unroll
  for (int i = 0; i < 4; ++i) r.u[i] ^= 0x80008000u;
  return r.s;
}

__device__ __forceinline__ f32x4 relu4(f32x4 v) {
  f32x4 r;
  #pragma unroll
  for (int j = 0; j < 4; ++j) r[j] = fmaxf(v[j], 0.0f);
  return r;
}

// ============ prep: weights f32 -> fp16 B-fragments in d_ws ============
// B-frag layout (16x16x32): lane l holds B[k = (l>>4)*8 + j][col = l&15], j=0..7.
__global__ __launch_bounds__(64) void prep_kernel(
    const float* b1w1, const float* b1w2, const float* lpw1, const float* lpw2,
    const float* a1win, const float* a1wout, const float* f1gw, const float* f1bw,
    const float* b2w1, const float* b2w2, const float* a2win, const float* a2wout,
    const float* f2gw, const float* f2bw, const float* b3w1, const float* b3w2,
    const float* outw, unsigned short* ws)
{
  const float* WS_[17] = {b1w1,b1w2,lpw1,lpw2,a1win,a1wout,f1gw,f1bw,b2w1,b2w2,
                          a2win,a2wout,f2gw,f2bw,b3w1,b3w2,outw};
  const int KA[17] = {80,64,40,32,64,64,64,64,64,64,64,64,64,64,64,64,64};
  const int NA[17] = {64,64,32,64,192,64,64,64,64,64,192,64,64,64,64,64,64};
  const int FO[17] = {0,12,20,24,28,52,60,68,76,84,92,116,124,132,140,148,156};

  const int b = blockIdx.x;
  int m = 0;
  #pragma unroll
  for (int i = 1; i < 17; ++i) if (b >= FO[i]) m = i;
  const int f  = b - FO[m];
  const int K  = KA[m], N = NA[m];
  const int kc = (K + 31) >> 5;
  const int n  = f / kc, c = f % kc;

  const int lane = threadIdx.x;
  const int col  = n * 16 + (lane & 15);
  const int kb   = c * 32 + ((lane >> 4) * 8);
  const float* W = WS_[m];

  short8 r;
  #pragma unroll
  for (int j = 0; j < 8; ++j) {
    const int k = kb + j;
    const float v = (k < K) ? W[(size_t)k * N + col] : 0.0f;
    r[j] = (short)f2h(v);
  }
  *reinterpret_cast<short8*>(ws + (size_t)b * 512 + lane * 8) = r;
}

// ============ main kernel helpers ============
// Per-wave LDS: 2 sub-tiles of 16 rows x stride 72 fp16 (1152 ushort each).
__device__ __forceinline__ short8 ldA(const unsigned short* Ab, int c) {
  return *reinterpret_cast<const short8*>(Ab + c * 32);
}
__device__ __forceinline__ void stC_pk(unsigned short* Cb, int n, unsigned int p01, unsigned int p23) {
  unsigned short* p = Cb + n * 16;
  p[0]   = (unsigned short)p01;
  p[72]  = (unsigned short)(p01 >> 16);   // ds_write_b16_d16_hi
  p[144] = (unsigned short)p23;
  p[216] = (unsigned short)(p23 >> 16);
}
__device__ __forceinline__ void stC(unsigned short* Cb, int n, f32x4 v) {
  stC_pk(Cb, n, pkrtz(v[0], v[1]), pkrtz(v[2], v[3]));
}
// sum over the 16-lane group, broadcast to all 16 lanes.
// DPP row_ror adds: VALU pipe (1 op/stage), not LDS pipe — replaces ds_swizzle chains.
// row_ror:N = dpp_ctrl 0x120+N; rows of 16 lanes match our head-dim groups exactly.
__device__ __forceinline__ float rowsum16(float v) {
  float r = v;
  r += __int_as_float(__builtin_amdgcn_update_dpp(
        __float_as_int(r), __float_as_int(r), 0x128, 0xf, 0xf, false)); // row_ror:8
  r += __int_as_float(__builtin_amdgcn_update_dpp(
        __float_as_int(r), __float_as_int(r), 0x124, 0xf, 0xf, false)); // row_ror:4
  r += __int_as_float(__builtin_amdgcn_update_dpp(
        __float_as_int(r), __float_as_int(r), 0x122, 0xf, 0xf, false)); // row_ror:2
  r += __int_as_float(__builtin_amdgcn_update_dpp(
        __float_as_int(r), __float_as_int(r), 0x121, 0xf, 0xf, false)); // row_ror:1
  return r;
}

// ============ main kernel: 4 waves/block, 32 rows/wave (2 independent 16-row chains) ============
__global__ __launch_bounds__(256, 4) void flow_mfma(
    const float* __restrict__ x, const float* __restrict__ t, const float* __restrict__ y,
    const float* __restrict__ b1b1, const float* __restrict__ b1b2,
    const float* __restrict__ lpb1, const float* __restrict__ lpb2,
    const float* __restrict__ a1bin, const float* __restrict__ a1bout,
    const float* __restrict__ f1gb, const float* __restrict__ f1bb,
    const float* __restrict__ b2b1, const float* __restrict__ b2b2,
    const float* __restrict__ a2bin, const float* __restrict__ a2bout,
    const float* __restrict__ f2gb, const float* __restrict__ f2bb,
    const float* __restrict__ b3b1, const float* __restrict__ b3b2,
    const float* __restrict__ outb,
    const unsigned short* __restrict__ ws,
    float* __restrict__ out, int Btotal)
{
  __shared__ __align__(16) unsigned short lds[4][2 * 16 * 72];
  const int tid  = threadIdx.x;
  const int lane = tid & 63, wid = tid >> 6;
  const int lrow = lane & 15, grp = lane >> 4;
  const int r0   = (blockIdx.x * 4 + wid) * 32;
  if (r0 >= Btotal) return;
  unsigned short* T = &lds[wid][0];
  unsigned short* Ab[2];
  unsigned short* Cb[2];
  #pragma unroll
  for (int u = 0; u < 2; ++u) {
    Ab[u] = T + u * 1152 + lrow * 72 + grp * 8;   // A-frag read base
    Cb[u] = T + u * 1152 + grp * 288 + lrow;      // C-frag write base
  }
  const short8* wsl = reinterpret_cast<const short8*>(ws) + lane;

  // ---- h80 A-frags: x (chunks 0,1) + time features (chunk 2, zero-padded 80..95)
  short8 hA0[2], hA1[2];
  {
    short8 tF[2];
    #pragma unroll
    for (int u = 0; u < 2; ++u) {
      const size_t row = (size_t)r0 + u * 16 + lrow;
      const float4* xp = reinterpret_cast<const float4*>(x + row * 64) + grp * 2;
      hA0[u] = pack8(xp[0], xp[1]);
      hA1[u] = pack8(xp[8], xp[9]);
      const float tv = t[row];
      float s = sinf(3.14159265358979323846f * tv);
      float c = cosf(3.14159265358979323846f * tv);
      short8 hp;
      #pragma unroll
      for (int j = 0; j < 8; ++j) {
        const float v = (grp == 0) ? s : ((grp == 1) ? c : 0.0f);
        hp[j] = (short)f2h(v);
        const float s2 = 2.0f * s * c;
        const float c2 = 1.0f - 2.0f * s * s;
        s = s2; c = c2;
      }
      tF[u] = hp;
    }
    // block1 w1 (K=80, ReLU)
    #pragma unroll
    for (int n = 0; n < 4; ++n) {
      const short8 B0 = wsl[(WS_B1W1 + n * 3 + 0) * 64];
      const short8 B1 = wsl[(WS_B1W1 + n * 3 + 1) * 64];
      const short8 B2 = wsl[(WS_B1W1 + n * 3 + 2) * 64];
      const float bias = b1b1[n * 16 + lrow];
      #pragma unroll
      for (int u = 0; u < 2; ++u) {
        f32x4 acc = {bias, bias, bias, bias};
        acc = MFMA16(hA0[u], B0, acc);
        acc = MFMA16(hA1[u], B1, acc);
        acc = MFMA16(tF[u],  B2, acc);
        stC(Cb[u], n, relu4(acc));
      }
    }
  }
  #pragma unroll
  for (int u = 0; u < 2; ++u) { hA0[u] = ldA(Ab[u], 0); hA1[u] = ldA(Ab[u], 1); }
  #pragma unroll
  for (int n = 0; n < 4; ++n) {
    const short8 B0 = wsl[(WS_B1W2 + n * 2 + 0) * 64];
    const short8 B1 = wsl[(WS_B1W2 + n * 2 + 1) * 64];
    const float bias = b1b2[n * 16 + lrow];
    #pragma unroll
    for (int u = 0; u < 2; ++u) {
      f32x4 acc = {bias, bias, bias, bias};
      acc = MFMA16(hA0[u], B0, acc);
      acc = MFMA16(hA1[u], B1, acc);
      stC(Cb[u], n, acc);
    }
  }
  #pragma unroll
  for (int u = 0; u < 2; ++u) { hA0[u] = ldA(Ab[u], 0); hA1[u] = ldA(Ab[u], 1); }

  // ---- label projection: ye = relu(y@lp_w1+b1) @ lp_w2 + b2
  short8 yeA0[2], yeA1[2];
  {
    short8 y0[2], y1[2];
    #pragma unroll
    for (int u = 0; u < 2; ++u) {
      const float* yrow = y + ((size_t)r0 + u * 16 + lrow) * 40;
      y0[u] = pack8(*reinterpret_cast<const float4*>(yrow + grp * 8),
                    *reinterpret_cast<const float4*>(yrow + grp * 8 + 4));
      y1[u] = (grp == 0) ? pack8(*reinterpret_cast<const float4*>(yrow + 32),
                                 *reinterpret_cast<const float4*>(yrow + 36))
                         : zero8();
    }
    #pragma unroll
    for (int n = 0; n < 2; ++n) {
      const short8 B0 = wsl[(WS_LPW1 + n * 2 + 0) * 64];
      const short8 B1 = wsl[(WS_LPW1 + n * 2 + 1) * 64];
      const float bias = lpb1[n * 16 + lrow];
      #pragma unroll
      for (int u = 0; u < 2; ++u) {
        f32x4 acc = {bias, bias, bias, bias};
        acc = MFMA16(y0[u], B0, acc);
        acc = MFMA16(y1[u], B1, acc);
        stC(Cb[u], n, relu4(acc));
      }
    }
    short8 z[2];
    #pragma unroll
    for (int u = 0; u < 2; ++u) z[u] = ldA(Ab[u], 0);
    #pragma unroll
    for (int n = 0; n < 4; ++n) {
      const short8 B0 = wsl[(WS_LPW2 + n) * 64];
      const float bias = lpb2[n * 16 + lrow];
      #pragma unroll
      for (int u = 0; u < 2; ++u)
        stC(Cb[u], n, MFMA16(z[u], B0, ((f32x4){bias, bias, bias, bias})));
    }
    #pragma unroll
    for (int u = 0; u < 2; ++u) { yeA0[u] = ldA(Ab[u], 0); yeA1[u] = ldA(Ab[u], 1); }
  }

  // ---- two reps of [attention -> FiLM -> residual block]
  // residual carry kept PACKED fp16 (2 uints per (n,u)) to save 16 VGPRs vs f32
  unsigned int hCp01[4][2], hCp23[4][2];
  #pragma unroll 1
  for (int rep = 0; rep < 2; ++rep) {
    const int WIN  = rep ? WS_A2WIN  : WS_A1WIN;
    const int WOUT = rep ? WS_A2WOUT : WS_A1WOUT;
    const int GW   = rep ? WS_F2GW   : WS_F1GW;
    const int BW   = rep ? WS_F2BW   : WS_F1BW;
    const int W1   = rep ? WS_B3W1   : WS_B2W1;
    const int W2   = rep ? WS_B3W2   : WS_B2W2;
    const float* binp  = rep ? a2bin  : a1bin;
    const float* boutp = rep ? a2bout : a1bout;
    const float* gbp   = rep ? f2gb   : f1gb;
    const float* fbp   = rep ? f2bb   : f1bb;
    const float* w1b   = rep ? b3b1   : b2b1;
    const float* w2b   = rep ? b3b2   : b2b2;

    // attention per head n. Phase 1: q,kd (frags Bq,Bk); phase 2: v (frags Bv).
    #pragma unroll 1
    for (int n = 0; n < 4; ++n) {
      float pr[2][4];
      {
        const short8 Bq0 = wsl[(WIN + n * 2 + 0) * 64];
        const short8 Bq1 = wsl[(WIN + n * 2 + 1) * 64];
        const short8 Bk0 = wsl[(WIN + (4 + n) * 2 + 0) * 64];
        const short8 Bk1 = wsl[(WIN + (4 + n) * 2 + 1) * 64];
        const float bq = binp[n * 16 + lrow];
        #pragma unroll
        for (int u = 0; u < 2; ++u) {
          f32x4 q = {bq, bq, bq, bq};
          q = MFMA16(hA0[u], Bq0, q);
          q = MFMA16(hA1[u], Bq1, q);
          f32x4 kd = {0.0f, 0.0f, 0.0f, 0.0f};
          kd = MFMA16(hA0[u], Bk0, kd);
          kd = MFMA16(hA1[u], Bk1, kd);
          kd = MFMA16(neg8(yeA0[u]), Bk0, kd);   // bias cancels in k0-k1
          kd = MFMA16(neg8(yeA1[u]), Bk1, kd);
          #pragma unroll
          for (int j = 0; j < 4; ++j) {
            const float d = rowsum16(q[j] * kd[j]);
            pr[u][j] = 1.0f / (1.0f + __expf(-0.25f * d));
          }
        }
      }
      {
        const short8 Bv0 = wsl[(WIN + (8 + n) * 2 + 0) * 64];
        const short8 Bv1 = wsl[(WIN + (8 + n) * 2 + 1) * 64];
        const float bv = binp[128 + n * 16 + lrow];
        #pragma unroll
        for (int u = 0; u < 2; ++u) {
          f32x4 v0 = {bv, bv, bv, bv}, v1 = {bv, bv, bv, bv};
          v0 = MFMA16(hA0[u],  Bv0, v0);
          v0 = MFMA16(hA1[u],  Bv1, v0);
          v1 = MFMA16(yeA0[u], Bv0, v1);
          v1 = MFMA16(yeA1[u], Bv1, v1);
          f32x4 ov;
          #pragma unroll
          for (int j = 0; j < 4; ++j) ov[j] = fmaf(pr[u][j], v0[j] - v1[j], v1[j]);
          stC(Cb[u], n, ov);
        }
      }
    }
    #pragma unroll
    for (int u = 0; u < 2; ++u) { hA0[u] = ldA(Ab[u], 0); hA1[u] = ldA(Ab[u], 1); }  // attn out

    // out-proj + FiLM; sequenced frag lifetimes (at -> g -> fb), carry packed fp16
    #pragma unroll
    for (int n = 0; n < 4; ++n) {
      f32x4 at[2], g[2];
      {
        const short8 Bo0 = wsl[(WOUT + n * 2 + 0) * 64];
        const short8 Bo1 = wsl[(WOUT + n * 2 + 1) * 64];
        const float bo = boutp[n * 16 + lrow];
        #pragma unroll
        for (int u = 0; u < 2; ++u) {
          at[u] = (f32x4){bo, bo, bo, bo};
          at[u] = MFMA16(hA0[u], Bo0, at[u]);
          at[u] = MFMA16(hA1[u], Bo1, at[u]);
        }
      }
      {
        const short8 Bg0 = wsl[(GW + n * 2 + 0) * 64];
        const short8 Bg1 = wsl[(GW + n * 2 + 1) * 64];
        const float bg = gbp[n * 16 + lrow];
        #pragma unroll
        for (int u = 0; u < 2; ++u) {
          g[u] = (f32x4){bg, bg, bg, bg};
          g[u] = MFMA16(yeA0[u], Bg0, g[u]);
          g[u] = MFMA16(yeA1[u], Bg1, g[u]);
        }
      }
      {
        const short8 Bb0 = wsl[(BW + n * 2 + 0) * 64];
        const short8 Bb1 = wsl[(BW + n * 2 + 1) * 64];
        const float bf = fbp[n * 16 + lrow];
        #pragma unroll
        for (int u = 0; u < 2; ++u) {
          f32x4 fb = {bf, bf, bf, bf};
          fb = MFMA16(yeA0[u], Bb0, fb);
          fb = MFMA16(yeA1[u], Bb1, fb);
          f32x4 hv;
          #pragma unroll
          for (int j = 0; j < 4; ++j) hv[j] = fmaf(g[u][j], at[u][j], fb[j]);
          const unsigned int p01 = pkrtz(hv[0], hv[1]);
          const unsigned int p23 = pkrtz(hv[2], hv[3]);
          hCp01[n][u] = p01; hCp23[n][u] = p23;
          stC_pk(Cb[u], n, p01, p23);
        }
      }
    }
    #pragma unroll
    for (int u = 0; u < 2; ++u) { hA0[u] = ldA(Ab[u], 0); hA1[u] = ldA(Ab[u], 1); }  // FiLM out

    // residual block: h = h + relu(h@w1+b1) @ w2 + b2
    #pragma unroll
    for (int n = 0; n < 4; ++n) {
      const short8 B0 = wsl[(W1 + n * 2 + 0) * 64];
      const short8 B1 = wsl[(W1 + n * 2 + 1) * 64];
      const float bias = w1b[n * 16 + lrow];
      #pragma unroll
      for (int u = 0; u < 2; ++u) {
        f32x4 acc = {bias, bias, bias, bias};
        acc = MFMA16(hA0[u], B0, acc);
        acc = MFMA16(hA1[u], B1, acc);
        stC(Cb[u], n, relu4(acc));
      }
    }
    #pragma unroll
    for (int u = 0; u < 2; ++u) { hA0[u] = ldA(Ab[u], 0); hA1[u] = ldA(Ab[u], 1); }  // u (hidden)
    #pragma unroll
    for (int n = 0; n < 4; ++n) {
      const short8 B0 = wsl[(W2 + n * 2 + 0) * 64];
      const short8 B1 = wsl[(W2 + n * 2 + 1) * 64];
      const float bias = w2b[n * 16 + lrow];
      #pragma unroll
      for (int u = 0; u < 2; ++u) {
        f32x4 acc = {bias, bias, bias, bias};
        acc = MFMA16(hA0[u], B0, acc);
        acc = MFMA16(hA1[u], B1, acc);
        acc[0] += h_lo(hCp01[n][u]);
        acc[1] += h_hi(hCp01[n][u]);
        acc[2] += h_lo(hCp23[n][u]);
        acc[3] += h_hi(hCp23[n][u]);
        stC(Cb[u], n, acc);
      }
    }
    #pragma unroll
    for (int u = 0; u < 2; ++u) { hA0[u] = ldA(Ab[u], 0); hA1[u] = ldA(Ab[u], 1); }  // next h
  }

  // ---- final projection + store (f32, coalesced 64B per 16-lane group)
  #pragma unroll 1
  for (int n = 0; n < 4; ++n) {
    const short8 B0 = wsl[(WS_OUTW + n * 2 + 0) * 64];
    const short8 B1 = wsl[(WS_OUTW + n * 2 + 1) * 64];
    const float bias = outb[n * 16 + lrow];
    #pragma unroll
    for (int u = 0; u < 2; ++u) {
      f32x4 a = {bias, bias, bias, bias};
      a = MFMA16(hA0[u], B0, a);
      a = MFMA16(hA1[u], B1, a);
      float* ob = out + ((size_t)r0 + u * 16 + grp * 4) * 64 + n * 16 + lrow;
      #pragma unroll
      for (int j = 0; j < 4; ++j)
        ob[j * 64] = a[j];
    }
  }
}

extern "C" void kernel_launch(void* const* d_in, const int* in_sizes, int n_in,
                              void* d_out, int out_size, void* d_ws, size_t ws_size,
                              hipStream_t stream) {
  (void)n_in; (void)out_size; (void)ws_size;
  const float* p[37];
  for (int i = 0; i < 37; ++i) p[i] = (const float*)d_in[i];
  unsigned short* ws = (unsigned short*)d_ws;

  prep_kernel<<<dim3(WS_FRAGS), dim3(64), 0, stream>>>(
      p[23], p[25], p[3], p[5], p[7], p[9], p[15], p[17],
      p[27], p[29], p[11], p[13], p[19], p[21], p[31], p[33], p[35], ws);

  const int B = in_sizes[0] / 64;
  const int grid = (B + 127) / 128;   // 128 rows per block (4 waves x 32)
  flow_mfma<<<dim3(grid), dim3(256), 0, stream>>>(
      p[0], p[1], p[2],
      p[24], p[26],          // b1_b1, b1_b2
      p[4],  p[6],           // lp_b1, lp_b2
      p[8],  p[10],          // a1_bin, a1_bout
      p[16], p[18],          // f1_gb, f1_bb
      p[28], p[30],          // b2_b1, b2_b2
      p[12], p[14],          // a2_bin, a2_bout
      p[20], p[22],          // f2_gb, f2_bb
      p[32], p[34],          // b3_b1, b3_b2
      p[36],                 // out_b
      ws, (float*)d_out, B);
}